// Round 12
// baseline (434.040 us; speedup 1.0000x reference)
//
#include <hip/hip_runtime.h>
#include <hip/hip_bf16.h>
#include <hip/hip_fp16.h>

#define N_NODES 100000
#define N_EDGES 3200000
#define NB      100
#define NPG     1000
#define EPG     32000    // edges per graph
#define DIN     128
#define DH      64
#define DE      32
#define NCLS    10
#define CNT_BLOCKS  832  // 8 slices x 104
#define SORT_BLOCKS 416  // 4 node-quarters x 104

// XCD-affine swizzle: graph g lives on XCD g%8. R14: packed (src|fp16 dinv)
// edge recs. R16: v_dot2 DOT8 MACs. R17: gemm1 on MFMA. R19: parallel CSR.
// R25: gemm2 on MFMA; smax folded into agg64/pool/head. 288.7us.
// Agg gather history: R20 straight unroll 56.5us BEST; R21-R24 all failed
// to beat it -> L2-latency x concurrency bound. CLOSED as a gather.
// R26/R27: layer-1 aggregation reformulated as DENSE-SLAB MFMA SpMM:
//   Out[64dst x 128ch] = Adj[64 x 1000] * H[1000 x 128ch]
// per 128-src slab: densify Adj in LDS (64 owner threads, fp16 RMW, dup
// edges accumulate), stage H-slab from h16t (TRANSPOSED gemm1 output,
// [g][ch][node] K-major -> staging is coalesced uint4 copies and BOTH mfma
// frags are single swizzled ds_read_b128 -- gemm1's proven W pattern).
// ~31x dense waste << ~200x MFMA speedup. R27: 4-way unrolled scatter loop
// (4 esrc loads in flight); R26 bench was an infra failure (container), no
// kernel diagnostics -- resubmission with hardening.

typedef _Float16 h2_t __attribute__((ext_vector_type(2)));
typedef _Float16 h8_t __attribute__((ext_vector_type(8)));
typedef float    f4_t __attribute__((ext_vector_type(4)));

__device__ __forceinline__ float dot2f(unsigned a, unsigned b, float c) {
#if __has_builtin(__builtin_amdgcn_fdot2)
    return __builtin_amdgcn_fdot2(__builtin_bit_cast(h2_t, a),
                                  __builtin_bit_cast(h2_t, b), c, false);
#else
    float d;
    asm("v_dot2_f32_f16 %0, %1, %2, %3" : "=v"(d) : "v"(a), "v"(b), "v"(c));
    return d;
#endif
}

// rA = edge A regs (halfs), rB = edge B, dv = half2(dvA, dvB).
#define DOT8(rA, rB, dv)                                                        \
    acc[0] = dot2f(__builtin_amdgcn_perm(rB.x, rA.x, 0x05040100u), dv, acc[0]); \
    acc[1] = dot2f(__builtin_amdgcn_perm(rB.x, rA.x, 0x07060302u), dv, acc[1]); \
    acc[2] = dot2f(__builtin_amdgcn_perm(rB.y, rA.y, 0x05040100u), dv, acc[2]); \
    acc[3] = dot2f(__builtin_amdgcn_perm(rB.y, rA.y, 0x07060302u), dv, acc[3]); \
    acc[4] = dot2f(__builtin_amdgcn_perm(rB.z, rA.z, 0x05040100u), dv, acc[4]); \
    acc[5] = dot2f(__builtin_amdgcn_perm(rB.z, rA.z, 0x07060302u), dv, acc[5]); \
    acc[6] = dot2f(__builtin_amdgcn_perm(rB.w, rA.w, 0x05040100u), dv, acc[6]); \
    acc[7] = dot2f(__builtin_amdgcn_perm(rB.w, rA.w, 0x07060302u), dv, acc[7]);

__device__ __forceinline__ unsigned fenc(float f) {
    unsigned u = __float_as_uint(f);
    return u ^ (unsigned)(((int)u >> 31) | (int)0x80000000);
}
__device__ __forceinline__ float fdec(unsigned key) {
    return (key & 0x80000000u) ? __uint_as_float(key ^ 0x80000000u)
                               : __uint_as_float(~key);
}

// ---------------- Phase 1: per-slice degree count ----------------

__global__ __launch_bounds__(256) void k_cnt(const int* __restrict__ dst,
                                             int* __restrict__ cnt8) {
    __shared__ int cnt[NPG];
    int slice = blockIdx.x >> 3;
    int g = (blockIdx.x & 7) + 8 * (slice % 13);
    int sub = slice / 13;                     // 0..7
    if (g >= NB) return;
    int t = threadIdx.x;
    for (int i = t; i < NPG; i += 256) cnt[i] = 0;
    __syncthreads();
    int ebase = g * EPG + sub * 4000, nbase = g * NPG;
    for (int i = t; i < 4000; i += 256)
        atomicAdd(&cnt[dst[ebase + i] - nbase], 1);
    __syncthreads();
    for (int i = t; i < NPG; i += 256)
        cnt8[sub * N_NODES + nbase + i] = cnt[i];
}

// ---------------- Phase 2: deg sum, scan -> rowptr, dinv/dh16 ----------------

__global__ __launch_bounds__(1024) void k_scan(const int* __restrict__ cnt8,
                                               int* __restrict__ rowptr,
                                               float* __restrict__ dinv,
                                               unsigned short* __restrict__ dh16) {
    __shared__ int sm[1024];
    int g = (blockIdx.x & 7) + 8 * (blockIdx.x >> 3);
    if (g >= NB) return;
    int t = threadIdx.x;
    int nbase = g * NPG, ebase = g * EPG;
    int v = 0;
    if (t < NPG) {
        #pragma unroll
        for (int s8 = 0; s8 < 8; s8++) v += cnt8[s8 * N_NODES + nbase + t];
        float dv = rsqrtf((float)v + 2.0f);
        dinv[nbase + t] = dv;
        dh16[nbase + t] = __half_as_ushort(__float2half_rn(dv));
    }
    sm[t] = v;
    __syncthreads();
    for (int off = 1; off < 1024; off <<= 1) {
        int xx = (t >= off) ? sm[t - off] : 0;
        __syncthreads();
        sm[t] += xx;
        __syncthreads();
    }
    if (t < NPG)
        rowptr[nbase + t] = ebase + sm[t] - v;
    if (g == NB - 1 && t == 0) rowptr[N_NODES] = N_EDGES;
}

// ---------------- Phase 3 fused: LDS-staged edge scatter + MFMA GEMM1 ----------------
// blocks [0,416): sort quarter (g,q). blocks [416,832): gemm1, 250 rows each.
// Edge record: uint32 = (src_local*16) | (fp16(dinv[src]) << 16).
// gemm1 writes h16t[g][ch][node] (TRANSPOSED, K-major) for the SpMM.

union SharedSG {
    struct {
        int cur[256];                            // LDS cursors (local offsets)
        unsigned buf[10000];                     // staged records
    } sc;
    struct {
        __align__(16) unsigned short wt[16384];  // fp16 W^T [c][k], swizzled
    } ge;
};

__global__ __launch_bounds__(1024) void k_sg(const int* __restrict__ src,
                                             const int* __restrict__ dst,
                                             const float* __restrict__ x,
                                             const float* __restrict__ Wa,
                                             const float* __restrict__ Wx,
                                             const int* __restrict__ rowptr,
                                             const unsigned short* __restrict__ dh16,
                                             unsigned int* __restrict__ esrc,
                                             unsigned short* __restrict__ h16t) {
    __shared__ SharedSG S;
    int t = threadIdx.x;
    if (blockIdx.x < SORT_BLOCKS) {
        // ---------------- scatter path ----------------
        int xcd = blockIdx.x & 7, slot = blockIdx.x >> 3;
        int g = xcd + 8 * (slot % 13);
        int q = slot / 13;                       // node quarter 0..3
        if (g >= NB) return;
        int nbase = g * NPG, ebase = g * EPG;
        int n0 = q * 250;
        int base0 = rowptr[nbase + n0];
        int cap = rowptr[nbase + n0 + 250] - base0;
        if (t < 250)
            S.sc.cur[t] = rowptr[nbase + n0 + t] - base0;
        __syncthreads();
        for (int i = t; i < EPG; i += 1024) {
            int d = dst[ebase + i] - nbase - n0;
            if ((unsigned)d < 250u) {
                int s = src[ebase + i];
                int pos = atomicAdd(&S.sc.cur[d], 1);
                S.sc.buf[pos] = ((unsigned)(s - nbase) * 16) |
                                ((unsigned)dh16[s] << 16);
            }
        }
        __syncthreads();
        for (int i = t; i < cap; i += 1024)
            esrc[base0 + i] = S.sc.buf[i];
    } else {
        // ------------- gemm1 path (MFMA): h16t = fp16( x @ [W_a1 | W_x1] )^T -------------
        int b2 = blockIdx.x - SORT_BLOCKS;         // 8*13*4 blocks
        int xcd = b2 & 7, slot = b2 >> 3;
        int g = xcd + 8 * (slot >> 2);
        int chunk = slot & 3;                       // 4 x 250-row chunks/graph
        if (g >= NB) return;
        int row0 = g * NPG + chunk * 250;
        // stage W^T fp16 in LDS, layout [c][k], byte ^= (c&7)<<4.
        {
            int cc = t & 127, kg = t >> 7;          // kg 0..7 -> k block of 16
            const float* Wp = (cc < 64) ? &Wa[cc] : &Wx[cc - 64];
            #pragma unroll
            for (int j = 0; j < 4; j++) {
                int k0 = kg * 16 + j * 4;
                union { __half h[4]; uint2 u; } pk;
                #pragma unroll
                for (int m = 0; m < 4; m++)
                    pk.h[m] = __float2half_rn(Wp[(k0 + m) * 64]);
                int byte = cc * 256 + ((2 * k0) ^ ((cc & 7) << 4));
                *(uint2*)((char*)S.ge.wt + byte) = pk.u;
            }
        }
        __syncthreads();
        int w = t >> 6, l = t & 63;
        int lr = l & 15, kq = l >> 4;               // A/B row|col, k-quarter
        int rowA = row0 + w * 16 + lr;
        int rA = rowA < N_NODES ? rowA : N_NODES - 1;
        const float* xr = &x[(size_t)rA * 128];
        h8_t a[4];
        #pragma unroll
        for (int kc = 0; kc < 4; kc++) {
            float4 lo = *(const float4*)&xr[kc * 32 + kq * 8];
            float4 hi = *(const float4*)&xr[kc * 32 + kq * 8 + 4];
            h8_t av;
            av[0] = (_Float16)lo.x; av[1] = (_Float16)lo.y;
            av[2] = (_Float16)lo.z; av[3] = (_Float16)lo.w;
            av[4] = (_Float16)hi.x; av[5] = (_Float16)hi.y;
            av[6] = (_Float16)hi.z; av[7] = (_Float16)hi.w;
            a[kc] = av;
        }
        f4_t acc[8] = {};
        #pragma unroll
        for (int kc = 0; kc < 4; kc++) {
            #pragma unroll
            for (int n = 0; n < 8; n++) {
                int cc = n * 16 + lr;
                int byte = cc * 256 + (((kc * 32 + kq * 8) * 2) ^ ((cc & 7) << 4));
                h8_t bf = *(h8_t*)((char*)S.ge.wt + byte);
                acc[n] = __builtin_amdgcn_mfma_f32_16x16x32_f16(a[kc], bf, acc[n], 0, 0, 0);
            }
        }
        // D: col = lane&15 (=lr) -> ch, row = 4*kq + reg -> node
        // write TRANSPOSED: h16t[(g*128 + ch)*1000 + nodeLocal]
        int nodeLoc = chunk * 250 + w * 16 + kq * 4;
        #pragma unroll
        for (int n = 0; n < 8; n++) {
            int ch = n * 16 + lr;
            unsigned short* hrow = h16t + ((size_t)g * 128 + ch) * 1000;
            #pragma unroll
            for (int j = 0; j < 4; j++) {
                int nl = nodeLoc + j;
                if (nl < NPG)
                    hrow[nl] = __half_as_ushort(__float2half_rn(acc[n][j]));
            }
        }
    }
}

// ---------------- Layer-1 aggregation as dense-slab MFMA SpMM ----------------
// Block = (graph g, 64-dst chunk). 256 thr = 4 waves; wave w owns m-tile w.
// Per 128-src slab: zero A + stage Bt (coalesced uint4, swizzled K-major),
// scatter edges (owner thread per dst row, fp16 RMW, 4-way unrolled loads),
// 32 MFMA/wave. Epilogue: di*acc + 2*di^2*h_self + bias, relu, fp16 store.

__global__ __launch_bounds__(256) void k_spmm128(const unsigned short* __restrict__ h16t,
                                                 const int* __restrict__ rowptr,
                                                 const unsigned int* __restrict__ esrc,
                                                 const float* __restrict__ dinv,
                                                 const float* __restrict__ ba,
                                                 const float* __restrict__ bx,
                                                 unsigned short* __restrict__ outB16) {
    __shared__ __align__(16) unsigned short As[8192];    // 64 dst x 128 src, swizzled
    __shared__ __align__(16) unsigned short Bt[16384];   // 128 ch x 128 src, swizzled
    int xcd = blockIdx.x & 7, slot = blockIdx.x >> 3;
    int gi = slot >> 4, chunk = slot & 15;
    int g = xcd + 8 * gi;
    if (g >= NB) return;
    int t = threadIdx.x;
    int w = t >> 6, l = t & 63, lr = l & 15, kq = l >> 4;
    int n0 = chunk * 64;                       // first dst node (local)
    // owner thread t<64 -> dst row t
    int eb0 = 0, eb1 = 0;
    if (t < 64) {
        int nl = n0 + t;
        if (nl < NPG) {
            int wid = g * NPG + nl;
            eb0 = rowptr[wid];
            eb1 = rowptr[wid + 1];
        }
    }
    const unsigned short* hb = h16t + (size_t)g * 128 * 1000;
    f4_t acc[8] = {};
    for (int sk = 0; sk < 8; sk++) {
        __syncthreads();                        // prev slab's MFMA done
        {   // zero A: 16KB / 256 thr = 64B each
            uint4 z = make_uint4(0, 0, 0, 0);
            #pragma unroll
            for (int i = 0; i < 4; i++)
                *(uint4*)((char*)As + t * 64 + i * 16) = z;
        }
        {   // stage Bt slab: ch row (t>>1), half (t&1): 8 uint4 each
            int tch = t >> 1, th = t & 1;
            #pragma unroll
            for (int i = 0; i < 8; i++) {
                int kl = th * 64 + i * 8;
                int nb = sk * 128 + kl;
                int nsrc = (nb + 8 <= NPG) ? nb : (NPG - 8);   // clamp tail (A cols 0 there)
                uint4 v = *(const uint4*)(hb + (size_t)tch * 1000 + nsrc);
                *(uint4*)((char*)Bt + tch * 256 + ((2 * kl) ^ ((tch & 7) << 4))) = v;
            }
        }
        __syncthreads();
        // scatter: edges with src in this slab; owner-serial fp16 RMW (dup edges add).
        // 4-way unrolled so the esrc loads issue together (MLP).
        if (t < 64) {
            int slo = sk << 7;
            int e = eb0;
            for (; e + 4 <= eb1; e += 4) {
                unsigned q0 = esrc[e], q1 = esrc[e + 1];
                unsigned q2 = esrc[e + 2], q3 = esrc[e + 3];
                #pragma unroll
                for (int j = 0; j < 4; j++) {
                    unsigned rec = (j == 0) ? q0 : (j == 1) ? q1 : (j == 2) ? q2 : q3;
                    int sl = (int)((rec & 0xffffu) >> 4) - slo;
                    if ((unsigned)sl < 128u) {
                        __half* ap = (__half*)((char*)As + t * 256 + ((2 * sl) ^ ((t & 7) << 4)));
                        *ap = __hadd(*ap, __ushort_as_half((unsigned short)(rec >> 16)));
                    }
                }
            }
            for (; e < eb1; e++) {
                unsigned rec = esrc[e];
                int sl = (int)((rec & 0xffffu) >> 4) - slo;
                if ((unsigned)sl < 128u) {
                    __half* ap = (__half*)((char*)As + t * 256 + ((2 * sl) ^ ((t & 7) << 4)));
                    *ap = __hadd(*ap, __ushort_as_half((unsigned short)(rec >> 16)));
                }
            }
        }
        __syncthreads();
        // MFMA: K=128 slab = 4 k-steps of 32; b128 frag reads (gemm1's pattern)
        #pragma unroll
        for (int kk = 0; kk < 4; kk++) {
            int row = w * 16 + lr;
            h8_t a = *(h8_t*)((char*)As + row * 256 + ((kk * 64 + kq * 16) ^ ((row & 7) << 4)));
            #pragma unroll
            for (int n = 0; n < 8; n++) {
                int ch = n * 16 + lr;
                h8_t b = *(h8_t*)((char*)Bt + ch * 256 + ((kk * 64 + kq * 16) ^ ((ch & 7) << 4)));
                acc[n] = __builtin_amdgcn_mfma_f32_16x16x32_f16(a, b, acc[n], 0, 0, 0);
            }
        }
    }
    // epilogue: D col=lr -> ch = n*16+lr; row = w*16 + kq*4 + j -> dst node
    int nodeBase = n0 + w * 16 + kq * 4;
    #pragma unroll
    for (int j = 0; j < 4; j++) {
        int nl = nodeBase + j;
        if (nl < NPG) {
            int wid = g * NPG + nl;
            float di = dinv[wid];
            float sw = 2.0f * di * di;
            #pragma unroll
            for (int n = 0; n < 8; n++) {
                int ch = n * 16 + lr;
                float hs = __half2float(__ushort_as_half(hb[(size_t)ch * 1000 + nl]));
                float bbv = (ch < 64) ? ba[ch] : bx[ch - 64];
                float o = fmaxf(di * acc[n][j] + sw * hs + bbv, 0.0f);
                outB16[(size_t)wid * 128 + ch] = __half_as_ushort(__float2half_rn(o));
            }
        }
    }
}

// ---------------- Aggregation, 64 channels (layer 2) + col-max partials ----------------
// R20 structure: 8-lane group = 1 node (uint4 row of 8), 32 nodes/block.
// R25: emits per-block col maxes (cols 0..31, LDS atomicMax) -> pmax.

__global__ __launch_bounds__(256) void k_agg64(const unsigned short* __restrict__ g16,
                                               const int* __restrict__ rowptr,
                                               const unsigned int* __restrict__ esrc,
                                               const float* __restrict__ dinv,
                                               const float* __restrict__ ba2,
                                               const float* __restrict__ bx2,
                                               float* __restrict__ s2,
                                               float* __restrict__ pmax) {
    __shared__ unsigned pm[32];
    int xcd = blockIdx.x & 7, slot = blockIdx.x >> 3;
    int gi = slot >> 5, chunk = slot & 31;        // 32 chunks x 32 nodes
    int g = xcd + 8 * gi;
    if (g >= NB) return;
    int t = threadIdx.x;
    if (t < 32) pm[t] = 0u;
    __syncthreads();
    int grp = t >> 3;              // node within block 0..31
    int cl  = t & 7;               // uint4 channel group
    int nl  = chunk * 32 + grp;
    int valid = nl < NPG;
    int nlc = valid ? nl : NPG - 1;
    int wid = g * NPG + nlc;
    const uint4* gg4 = (const uint4*)(g16 + (size_t)g * NPG * 64);
    float acc[8] = {};
    union U8 { uint4 u; __half h[8]; };
    int e0 = rowptr[wid];
    int e1 = valid ? rowptr[wid + 1] : e0;
    int e = e0;
    for (; e + 8 <= e1; e += 8) {
        unsigned pv0 = esrc[e + 0], pv1 = esrc[e + 1];
        unsigned pv2 = esrc[e + 2], pv3 = esrc[e + 3];
        unsigned pv4 = esrc[e + 4], pv5 = esrc[e + 5];
        unsigned pv6 = esrc[e + 6], pv7 = esrc[e + 7];
        uint4 r0 = gg4[((pv0 & 0xffffu) >> 1) + cl];
        uint4 r1 = gg4[((pv1 & 0xffffu) >> 1) + cl];
        uint4 r2 = gg4[((pv2 & 0xffffu) >> 1) + cl];
        uint4 r3 = gg4[((pv3 & 0xffffu) >> 1) + cl];
        uint4 r4 = gg4[((pv4 & 0xffffu) >> 1) + cl];
        uint4 r5 = gg4[((pv5 & 0xffffu) >> 1) + cl];
        uint4 r6 = gg4[((pv6 & 0xffffu) >> 1) + cl];
        uint4 r7 = gg4[((pv7 & 0xffffu) >> 1) + cl];
        unsigned dA = __builtin_amdgcn_perm(pv1, pv0, 0x07060302u);
        unsigned dB = __builtin_amdgcn_perm(pv3, pv2, 0x07060302u);
        unsigned dC = __builtin_amdgcn_perm(pv5, pv4, 0x07060302u);
        unsigned dD = __builtin_amdgcn_perm(pv7, pv6, 0x07060302u);
        DOT8(r0, r1, dA);
        DOT8(r2, r3, dB);
        DOT8(r4, r5, dC);
        DOT8(r6, r7, dD);
    }
    for (; e + 2 <= e1; e += 2) {
        unsigned pv0 = esrc[e], pv1 = esrc[e + 1];
        uint4 r0 = gg4[((pv0 & 0xffffu) >> 1) + cl];
        uint4 r1 = gg4[((pv1 & 0xffffu) >> 1) + cl];
        unsigned dA = __builtin_amdgcn_perm(pv1, pv0, 0x07060302u);
        DOT8(r0, r1, dA);
    }
    if (e < e1) {
        unsigned pv = esrc[e];
        uint4 r = gg4[((pv & 0xffffu) >> 1) + cl];
        unsigned dA = pv >> 16;
        DOT8(r, r, dA);
    }
    float di = dinv[wid];
    float sw = 2.0f * di * di;
    U8 hv; hv.u = gg4[nlc * 8 + cl];
    int cl8 = cl * 8;
    float o[8];
    #pragma unroll
    for (int k = 0; k < 8; k++)
        o[k] = di * acc[k] + sw * __half2float(hv.h[k]);
    if (cl8 < 32) {
        #pragma unroll
        for (int k = 0; k < 8; k++) o[k] += ba2[cl8 + k];
    } else {
        #pragma unroll
        for (int k = 0; k < 8; k++) o[k] = fmaxf(o[k] + bx2[cl8 - 32 + k], 0.0f);
    }
    if (valid) {
        *(float4*)&s2[(size_t)wid * 64 + cl8]     = make_float4(o[0], o[1], o[2], o[3]);
        *(float4*)&s2[(size_t)wid * 64 + cl8 + 4] = make_float4(o[4], o[5], o[6], o[7]);
    }
    if (valid && cl < 4) {
        #pragma unroll
        for (int k = 0; k < 8; k++)
            atomicMax(&pm[cl8 + k], fenc(o[k]));
    }
    __syncthreads();
    if (t < 32)
        pmax[((size_t)g * 32 + chunk) * 32 + t] = fdec(pm[t]);
}

// ---------------- GEMM 2 (MFMA): g16 = fp16( b16 @ Wpad[128][64] ) ----------------

__global__ __launch_bounds__(256) void k_gemm2(const unsigned short* __restrict__ Bm16,
                                               const float* __restrict__ Wa2,
                                               const float* __restrict__ Wx2,
                                               unsigned short* __restrict__ g16) {
    __shared__ __align__(16) unsigned short wt2[8192];   // 64 cols x 128 k, 16KB
    int xcd = blockIdx.x & 7, slot = blockIdx.x >> 3;
    int g = xcd + 8 * (slot >> 4);
    int chunk = slot & 15;
    if (g >= NB) return;
    int row0 = g * NPG + chunk * 64;   // chunk 15 spills into next graph: benign dup
    int t = threadIdx.x;
    {
        int cc = t & 63, kg = t >> 6;          // kg 0..3 -> k block of 32
        #pragma unroll
        for (int j = 0; j < 8; j++) {
            int k0 = kg * 32 + j * 4;
            union { __half h[4]; uint2 u; } pk;
            #pragma unroll
            for (int m = 0; m < 4; m++) {
                int k = k0 + m;
                float v;
                if (cc < 32) v = (k < 64)  ? Wa2[k * 32 + cc] : 0.0f;
                else         v = (k >= 64) ? Wx2[(k - 64) * 32 + (cc - 32)] : 0.0f;
                pk.h[m] = __float2half_rn(v);
            }
            int byte = cc * 256 + ((2 * k0) ^ ((cc & 7) << 4));
            *(uint2*)((char*)wt2 + byte) = pk.u;
        }
    }
    __syncthreads();
    int w = t >> 6, l = t & 63;
    int lr = l & 15, kq = l >> 4;
    int rowA = row0 + w * 16 + lr;
    int rA = rowA < N_NODES ? rowA : N_NODES - 1;
    const unsigned short* xr = &Bm16[(size_t)rA * 128];
    h8_t a[4];
    #pragma unroll
    for (int kc = 0; kc < 4; kc++)
        a[kc] = *(const h8_t*)&xr[kc * 32 + kq * 8];
    f4_t acc[4] = {};
    #pragma unroll
    for (int kc = 0; kc < 4; kc++) {
        #pragma unroll
        for (int n = 0; n < 4; n++) {
            int cc = n * 16 + lr;
            int byte = cc * 256 + (((kc * 32 + kq * 8) * 2) ^ ((cc & 7) << 4));
            h8_t bf = *(h8_t*)((char*)wt2 + byte);
            acc[n] = __builtin_amdgcn_mfma_f32_16x16x32_f16(a[kc], bf, acc[n], 0, 0, 0);
        }
    }
    int rowD = row0 + w * 16 + kq * 4;
    #pragma unroll
    for (int n = 0; n < 4; n++) {
        #pragma unroll
        for (int j = 0; j < 4; j++) {
            int r = rowD + j;
            if (r < N_NODES)
                g16[(size_t)r * 64 + n * 16 + lr] =
                    __half_as_ushort(__float2half_rn(acc[n][j]));
        }
    }
}

// ---------------- Bilinear pool: 8 chunks/graph; reduces pmax, emits psum ----------------

__global__ __launch_bounds__(256) void k_pool(const float* __restrict__ s2,
                                              const float* __restrict__ pmax,
                                              float* __restrict__ psum,
                                              float* __restrict__ prods) {
    __shared__ float ta[25][32];
    __shared__ float tx[25][32];
    __shared__ float gm[32];
    int xcd = blockIdx.x & 7, slot = blockIdx.x >> 3;
    int g = xcd + 8 * (slot >> 3);
    int ch = slot & 7;
    if (g >= NB) return;
    int t = threadIdx.x;
    if (t < 32) {
        float m = -1e30f;
        for (int j = 0; j < 32; j++)
            m = fmaxf(m, pmax[((size_t)g * 32 + j) * 32 + t]);
        gm[t] = m;
    }
    int e  = t >> 3;
    int f4 = t & 7;
    float a0 = 0.f, a1 = 0.f, a2 = 0.f, a3 = 0.f;
    float csum = 0.f;
    int base = g * NPG + ch * 125;
    for (int n0 = 0; n0 < 125; n0 += 25) {
        __syncthreads();
        for (int i = t; i < 25 * 16; i += 256) {
            int r = i >> 4, c4 = i & 15;
            float4 v = *(const float4*)&s2[(size_t)(base + n0 + r) * 64 + c4 * 4];
            if (c4 < 8) {
                int cb = c4 * 4;
                v.x = __expf(v.x - gm[cb + 0]);
                v.y = __expf(v.y - gm[cb + 1]);
                v.z = __expf(v.z - gm[cb + 2]);
                v.w = __expf(v.w - gm[cb + 3]);
                *(float4*)&ta[r][cb] = v;
            } else {
                *(float4*)&tx[r][(c4 - 8) * 4] = v;
            }
        }
        __syncthreads();
        if (t < 32) {
            #pragma unroll 5
            for (int r = 0; r < 25; r++) csum += ta[r][t];
        }
        #pragma unroll 5
        for (int n = 0; n < 25; n++) {
            float a   = ta[n][e];
            float4 xv = *(float4*)&tx[n][f4 * 4];
            a0 += a * xv.x; a1 += a * xv.y; a2 += a * xv.z; a3 += a * xv.w;
        }
    }
    if (t < 32)
        psum[((size_t)g * 8 + ch) * 32 + t] = csum;
    *(float4*)&prods[((size_t)(g * 8 + ch)) * 1024 + e * 32 + f4 * 4] =
        make_float4(a0, a1, a2, a3);
}

// ---------------- Head: fold psum -> 1/s, sum 8 chunk-partials, linear, softmax ----------------

__global__ __launch_bounds__(256) void k_head(const float* __restrict__ prods,
                                              const float* __restrict__ psum,
                                              const float* __restrict__ Wlin,
                                              const float* __restrict__ blin,
                                              float* __restrict__ out) {
    __shared__ float red[4][NCLS];
    __shared__ float sinvv[32];
    int g = (blockIdx.x & 7) + 8 * (blockIdx.x >> 3);
    if (g >= NB) return;
    int t = threadIdx.x;
    if (t < 32) {
        float s = 0.f;
        for (int q = 0; q < 8; q++) s += psum[((size_t)g * 8 + q) * 32 + t];
        sinvv[t] = 1.0f / s;
    }
    __syncthreads();
    float p[NCLS];
    for (int c = 0; c < NCLS; c++) p[c] = 0.0f;
    const float* pg = &prods[(size_t)g * 8 * 1024];
    for (int j = 0; j < 4; j++) {
        int k = t * 4 + j;
        int e = k >> 5;
        float v = 0.0f;
        #pragma unroll
        for (int q = 0; q < 8; q++) v += pg[q * 1024 + k];
        v *= sinvv[e];
        const float* wrow = &Wlin[k * NCLS];
        for (int c = 0; c < NCLS; c++) p[c] += v * wrow[c];
    }
    for (int off = 32; off > 0; off >>= 1)
        for (int c = 0; c < NCLS; c++) p[c] += __shfl_down(p[c], off, 64);
    int wave = t >> 6, lane = t & 63;
    if (lane == 0)
        for (int c = 0; c < NCLS; c++) red[wave][c] = p[c];
    __syncthreads();
    if (t == 0) {
        float logits[NCLS]; float mx = -1e30f;
        for (int c = 0; c < NCLS; c++) {
            logits[c] = red[0][c] + red[1][c] + red[2][c] + red[3][c] + blin[c];
            mx = fmaxf(mx, logits[c]);
        }
        float s = 0.0f;
        for (int c = 0; c < NCLS; c++) { logits[c] = expf(logits[c] - mx); s += logits[c]; }
        float inv = 1.0f / s;
        for (int c = 0; c < NCLS; c++) out[g * NCLS + c] = logits[c] * inv;
    }
}

// ---------------- launch ----------------

extern "C" void kernel_launch(void* const* d_in, const int* in_sizes, int n_in,
                              void* d_out, int out_size, void* d_ws, size_t ws_size,
                              hipStream_t stream) {
    const float* x    = (const float*)d_in[0];
    const int*   ei   = (const int*)d_in[1];
    const float* Wa1  = (const float*)d_in[3];
    const float* ba1  = (const float*)d_in[4];
    const float* Wa2  = (const float*)d_in[5];
    const float* ba2  = (const float*)d_in[6];
    const float* Wx1  = (const float*)d_in[7];
    const float* bx1  = (const float*)d_in[8];
    const float* Wx2  = (const float*)d_in[9];
    const float* bx2  = (const float*)d_in[10];
    const float* Wlin = (const float*)d_in[11];
    const float* blin = (const float*)d_in[12];
    float* out = (float*)d_out;

    char* w = (char*)d_ws;
    auto alloc = [&](size_t bytes) -> void* {
        void* p = (void*)w;
        w += (bytes + 255) & ~(size_t)255;
        return p;
    };
    int*            rowptr = (int*)alloc((N_NODES + 1) * sizeof(int));
    int*            cnt8   = (int*)alloc((size_t)8 * N_NODES * sizeof(int));
    float*          dinv   = (float*)alloc(N_NODES * sizeof(float));
    unsigned short* dh16   = (unsigned short*)alloc(N_NODES * sizeof(unsigned short));
    unsigned int*   esrc   = (unsigned int*)alloc((size_t)N_EDGES * sizeof(unsigned int));
    float*          pmax   = (float*)alloc((size_t)NB * 32 * 32 * sizeof(float));
    float*          psum   = (float*)alloc((size_t)NB * 8 * 32 * sizeof(float));
    float*          prods  = (float*)alloc((size_t)NB * 8 * 1024 * sizeof(float));
    unsigned short* h16t   = (unsigned short*)alloc((size_t)N_NODES * 128 * sizeof(unsigned short));
    unsigned short* b16    = (unsigned short*)alloc((size_t)N_NODES * 128 * sizeof(unsigned short));
    unsigned short* g16    = (unsigned short*)alloc((size_t)N_NODES * 64 * sizeof(unsigned short));
    float*          s2     = (float*)alloc((size_t)N_NODES * 64 * sizeof(float));

    const int* srcp = ei;
    const int* dstp = ei + N_EDGES;

    k_cnt<<<CNT_BLOCKS, 256, 0, stream>>>(dstp, cnt8);
    k_scan<<<8 * 13, 1024, 0, stream>>>(cnt8, rowptr, dinv, dh16);
    k_sg<<<SORT_BLOCKS + 8 * 13 * 4, 1024, 0, stream>>>(srcp, dstp, x, Wa1, Wx1,
                                                        rowptr, dh16, esrc, h16t);
    k_spmm128<<<8 * 13 * 16, 256, 0, stream>>>(h16t, rowptr, esrc, dinv, ba1, bx1, b16);
    k_gemm2<<<8 * 13 * 16, 256, 0, stream>>>(b16, Wa2, Wx2, g16);
    k_agg64<<<8 * 13 * 32, 256, 0, stream>>>(g16, rowptr, esrc, dinv, ba2, bx2, s2, pmax);
    k_pool<<<8 * 13 * 8, 256, 0, stream>>>(s2, pmax, psum, prods);
    k_head<<<8 * 13, 256, 0, stream>>>(prods, psum, Wlin, blin, out);
}

// Round 13
// 307.177 us; speedup vs baseline: 1.4130x; 1.4130x over previous
//
#include <hip/hip_runtime.h>
#include <hip/hip_bf16.h>
#include <hip/hip_fp16.h>

#define N_NODES 100000
#define N_EDGES 3200000
#define NB      100
#define NPG     1000
#define EPG     32000    // edges per graph
#define DIN     128
#define DH      64
#define DE      32
#define NCLS    10
#define CNT_BLOCKS  832  // 8 slices x 104
#define SORT_BLOCKS 832  // 8 node-eighths x 104 (R28: was 4 quarters)

// XCD-affine swizzle: graph g lives on XCD g%8. Aggregation = PULL gather
// from L2. R14: packed (src|fp16 dinv) edge recs. R16: MACs via
// v_dot2_f32_f16 (DOT8). R17: gemm1 on MFMA. R19: parallel CSR build.
// Agg history: R20 group-per-node straight 8-edge unroll = 56.5us BEST.
// R21 depth-8 pipeline FAILED (VGPR cliff). R22 LDS staging FAILED (occ).
// R23 channel-split NULL. R24 launch-bounds cap FAILED (scratch spills).
// R26/R27 dense-slab MFMA SpMM FAILED (181us: owner-scatter = serial LDS
// RMW with 8-way bank conflicts + 8x edge rescan; 15.9M conflicts).
// Aggregation is CLOSED as an L2-latency-bound gather at ~57us.
// R25 (proven 288.7us): gemm2 on MFMA (padded 128x64 block-diag W);
// k_smax deleted -- agg64 emits per-chunk col maxes -> pmax; pool reduces
// pmax + accumulates per-chunk exp-sums -> psum; head folds psum.
// R28 = R25 + sort split 4->8 blocks/graph (halve per-block serial LDS
// atomics, double TLP; sort LDS 41->25KB). R19 measured 1->4 as a win.

typedef _Float16 h2_t __attribute__((ext_vector_type(2)));
typedef _Float16 h8_t __attribute__((ext_vector_type(8)));
typedef float    f4_t __attribute__((ext_vector_type(4)));

__device__ __forceinline__ float dot2f(unsigned a, unsigned b, float c) {
#if __has_builtin(__builtin_amdgcn_fdot2)
    return __builtin_amdgcn_fdot2(__builtin_bit_cast(h2_t, a),
                                  __builtin_bit_cast(h2_t, b), c, false);
#else
    float d;
    asm("v_dot2_f32_f16 %0, %1, %2, %3" : "=v"(d) : "v"(a), "v"(b), "v"(c));
    return d;
#endif
}

// rA = edge A regs (halfs), rB = edge B, dv = half2(dvA, dvB).
// perm sel: src1 bytes are idx 0..3, src0 bytes idx 4..7.
#define DOT8(rA, rB, dv)                                                        \
    acc[0] = dot2f(__builtin_amdgcn_perm(rB.x, rA.x, 0x05040100u), dv, acc[0]); \
    acc[1] = dot2f(__builtin_amdgcn_perm(rB.x, rA.x, 0x07060302u), dv, acc[1]); \
    acc[2] = dot2f(__builtin_amdgcn_perm(rB.y, rA.y, 0x05040100u), dv, acc[2]); \
    acc[3] = dot2f(__builtin_amdgcn_perm(rB.y, rA.y, 0x07060302u), dv, acc[3]); \
    acc[4] = dot2f(__builtin_amdgcn_perm(rB.z, rA.z, 0x05040100u), dv, acc[4]); \
    acc[5] = dot2f(__builtin_amdgcn_perm(rB.z, rA.z, 0x07060302u), dv, acc[5]); \
    acc[6] = dot2f(__builtin_amdgcn_perm(rB.w, rA.w, 0x05040100u), dv, acc[6]); \
    acc[7] = dot2f(__builtin_amdgcn_perm(rB.w, rA.w, 0x07060302u), dv, acc[7]);

__device__ __forceinline__ unsigned fenc(float f) {
    unsigned u = __float_as_uint(f);
    return u ^ (unsigned)(((int)u >> 31) | (int)0x80000000);
}
__device__ __forceinline__ float fdec(unsigned key) {
    return (key & 0x80000000u) ? __uint_as_float(key ^ 0x80000000u)
                               : __uint_as_float(~key);
}

// ---------------- Phase 1: per-slice degree count ----------------

__global__ __launch_bounds__(256) void k_cnt(const int* __restrict__ dst,
                                             int* __restrict__ cnt8) {
    __shared__ int cnt[NPG];
    int slice = blockIdx.x >> 3;
    int g = (blockIdx.x & 7) + 8 * (slice % 13);
    int sub = slice / 13;                     // 0..7
    if (g >= NB) return;
    int t = threadIdx.x;
    for (int i = t; i < NPG; i += 256) cnt[i] = 0;
    __syncthreads();
    int ebase = g * EPG + sub * 4000, nbase = g * NPG;
    for (int i = t; i < 4000; i += 256)
        atomicAdd(&cnt[dst[ebase + i] - nbase], 1);
    __syncthreads();
    for (int i = t; i < NPG; i += 256)
        cnt8[sub * N_NODES + nbase + i] = cnt[i];
}

// ---------------- Phase 2: deg sum, scan -> rowptr, dinv/dh16 ----------------

__global__ __launch_bounds__(1024) void k_scan(const int* __restrict__ cnt8,
                                               int* __restrict__ rowptr,
                                               float* __restrict__ dinv,
                                               unsigned short* __restrict__ dh16) {
    __shared__ int sm[1024];
    int g = (blockIdx.x & 7) + 8 * (blockIdx.x >> 3);
    if (g >= NB) return;
    int t = threadIdx.x;
    int nbase = g * NPG, ebase = g * EPG;
    int v = 0;
    if (t < NPG) {
        #pragma unroll
        for (int s8 = 0; s8 < 8; s8++) v += cnt8[s8 * N_NODES + nbase + t];
        float dv = rsqrtf((float)v + 2.0f);
        dinv[nbase + t] = dv;
        dh16[nbase + t] = __half_as_ushort(__float2half_rn(dv));
    }
    sm[t] = v;
    __syncthreads();
    for (int off = 1; off < 1024; off <<= 1) {
        int xx = (t >= off) ? sm[t - off] : 0;
        __syncthreads();
        sm[t] += xx;
        __syncthreads();
    }
    if (t < NPG)
        rowptr[nbase + t] = ebase + sm[t] - v;
    if (g == NB - 1 && t == 0) rowptr[N_NODES] = N_EDGES;
}

// ---------------- Phase 3 fused: LDS-staged edge scatter + MFMA GEMM1 ----------------
// blocks [0,832): sort eighth (g,q) -- nodes [q*125,(q+1)*125).
// blocks [832, 832+416): gemm1, 250 rows each.
// Edge record: uint32 = (src_local*16) | (fp16(dinv[src]) << 16).

union SharedSG {
    struct {
        int cur[128];                            // LDS cursors (local offsets)
        unsigned buf[6000];                      // staged records (~4000 + 33 sigma)
    } sc;
    struct {
        __align__(16) unsigned short wt[16384];  // fp16 W^T [c][k], swizzled
    } ge;
};

__global__ __launch_bounds__(1024) void k_sg(const int* __restrict__ src,
                                             const int* __restrict__ dst,
                                             const float* __restrict__ x,
                                             const float* __restrict__ Wa,
                                             const float* __restrict__ Wx,
                                             const int* __restrict__ rowptr,
                                             const unsigned short* __restrict__ dh16,
                                             unsigned int* __restrict__ esrc,
                                             unsigned short* __restrict__ h16) {
    __shared__ SharedSG S;
    int t = threadIdx.x;
    if (blockIdx.x < SORT_BLOCKS) {
        // ---------------- scatter path ----------------
        int xcd = blockIdx.x & 7, slot = blockIdx.x >> 3;
        int g = xcd + 8 * (slot % 13);
        int q = slot / 13;                       // node eighth 0..7
        if (g >= NB) return;
        int nbase = g * NPG, ebase = g * EPG;
        int n0 = q * 125;
        int base0 = rowptr[nbase + n0];
        int cap = rowptr[nbase + n0 + 125] - base0;
        if (t < 125)
            S.sc.cur[t] = rowptr[nbase + n0 + t] - base0;
        __syncthreads();
        for (int i = t; i < EPG; i += 1024) {
            int d = dst[ebase + i] - nbase - n0;
            if ((unsigned)d < 125u) {
                int s = src[ebase + i];
                int pos = atomicAdd(&S.sc.cur[d], 1);
                S.sc.buf[pos] = ((unsigned)(s - nbase) * 16) |
                                ((unsigned)dh16[s] << 16);
            }
        }
        __syncthreads();
        for (int i = t; i < cap; i += 1024)
            esrc[base0 + i] = S.sc.buf[i];
    } else {
        // ------------- gemm1 path (MFMA): h16 = fp16( x @ [W_a1 | W_x1] ) -------------
        int b2 = blockIdx.x - SORT_BLOCKS;         // 8*13*4 blocks
        int xcd = b2 & 7, slot = b2 >> 3;
        int g = xcd + 8 * (slot >> 2);
        int chunk = slot & 3;                       // 4 x 250-row chunks/graph
        if (g >= NB) return;
        int row0 = g * NPG + chunk * 250;
        // stage W^T fp16 in LDS, layout [c][k], byte ^= (c&7)<<4.
        {
            int cc = t & 127, kg = t >> 7;          // kg 0..7 -> k block of 16
            const float* Wp = (cc < 64) ? &Wa[cc] : &Wx[cc - 64];
            #pragma unroll
            for (int j = 0; j < 4; j++) {
                int k0 = kg * 16 + j * 4;
                union { __half h[4]; uint2 u; } pk;
                #pragma unroll
                for (int m = 0; m < 4; m++)
                    pk.h[m] = __float2half_rn(Wp[(k0 + m) * 64]);
                int byte = cc * 256 + ((2 * k0) ^ ((cc & 7) << 4));
                *(uint2*)((char*)S.ge.wt + byte) = pk.u;
            }
        }
        __syncthreads();
        int w = t >> 6, l = t & 63;
        int lr = l & 15, kq = l >> 4;               // A/B row|col, k-quarter
        int rowA = row0 + w * 16 + lr;
        int rA = rowA < N_NODES ? rowA : N_NODES - 1;
        const float* xr = &x[(size_t)rA * 128];
        h8_t a[4];
        #pragma unroll
        for (int kc = 0; kc < 4; kc++) {
            float4 lo = *(const float4*)&xr[kc * 32 + kq * 8];
            float4 hi = *(const float4*)&xr[kc * 32 + kq * 8 + 4];
            h8_t av;
            av[0] = (_Float16)lo.x; av[1] = (_Float16)lo.y;
            av[2] = (_Float16)lo.z; av[3] = (_Float16)lo.w;
            av[4] = (_Float16)hi.x; av[5] = (_Float16)hi.y;
            av[6] = (_Float16)hi.z; av[7] = (_Float16)hi.w;
            a[kc] = av;
        }
        f4_t acc[8] = {};
        #pragma unroll
        for (int kc = 0; kc < 4; kc++) {
            #pragma unroll
            for (int n = 0; n < 8; n++) {
                int cc = n * 16 + lr;
                int byte = cc * 256 + (((kc * 32 + kq * 8) * 2) ^ ((cc & 7) << 4));
                h8_t bf = *(h8_t*)((char*)S.ge.wt + byte);
                acc[n] = __builtin_amdgcn_mfma_f32_16x16x32_f16(a[kc], bf, acc[n], 0, 0, 0);
            }
        }
        // D: col = lane&15 (=lr), row = 4*kq + reg
        int rowD = row0 + w * 16 + kq * 4;
        #pragma unroll
        for (int n = 0; n < 8; n++) {
            #pragma unroll
            for (int j = 0; j < 4; j++) {
                int r = rowD + j;
                if (r < N_NODES)
                    h16[(size_t)r * 128 + n * 16 + lr] =
                        __half_as_ushort(__float2half_rn(acc[n][j]));
            }
        }
    }
}

// ---------------- Aggregation, 128 channels (layer 1) ----------------
// R20 structure (proven 56.5us): 16-lane group = 1 node; lane owns 8
// channels (uint4). 16 nodes/block, no cross-lane reduction, straight
// 8-edge unroll. No launch-bounds min-waves (R24's spill lesson).

__global__ __launch_bounds__(256) void k_agg128(const unsigned short* __restrict__ h16,
                                                const int* __restrict__ rowptr,
                                                const unsigned int* __restrict__ esrc,
                                                const float* __restrict__ dinv,
                                                const float* __restrict__ ba,
                                                const float* __restrict__ bx,
                                                unsigned short* __restrict__ outB16) {
    int xcd = blockIdx.x & 7, slot = blockIdx.x >> 3;
    int gi = slot / 63, chunk = slot - gi * 63;   // 63 chunks x 16 nodes
    int g = xcd + 8 * gi;
    if (g >= NB) return;
    int grp = threadIdx.x >> 4;    // node within block 0..15
    int cl  = threadIdx.x & 15;    // uint4 channel group
    int nl  = chunk * 16 + grp;
    int valid = nl < NPG;
    int nlc = valid ? nl : NPG - 1;
    int wid = g * NPG + nlc;
    const uint4* hg4 = (const uint4*)(h16 + (size_t)g * NPG * 128);
    float acc[8] = {};
    union U8 { uint4 u; __half h[8]; };
    int e0 = rowptr[wid];
    int e1 = valid ? rowptr[wid + 1] : e0;
    int e = e0;
    for (; e + 8 <= e1; e += 8) {
        unsigned pv0 = esrc[e + 0], pv1 = esrc[e + 1];
        unsigned pv2 = esrc[e + 2], pv3 = esrc[e + 3];
        unsigned pv4 = esrc[e + 4], pv5 = esrc[e + 5];
        unsigned pv6 = esrc[e + 6], pv7 = esrc[e + 7];
        uint4 r0 = hg4[(pv0 & 0xffffu) + cl];
        uint4 r1 = hg4[(pv1 & 0xffffu) + cl];
        uint4 r2 = hg4[(pv2 & 0xffffu) + cl];
        uint4 r3 = hg4[(pv3 & 0xffffu) + cl];
        uint4 r4 = hg4[(pv4 & 0xffffu) + cl];
        uint4 r5 = hg4[(pv5 & 0xffffu) + cl];
        uint4 r6 = hg4[(pv6 & 0xffffu) + cl];
        uint4 r7 = hg4[(pv7 & 0xffffu) + cl];
        unsigned dA = __builtin_amdgcn_perm(pv1, pv0, 0x07060302u);
        unsigned dB = __builtin_amdgcn_perm(pv3, pv2, 0x07060302u);
        unsigned dC = __builtin_amdgcn_perm(pv5, pv4, 0x07060302u);
        unsigned dD = __builtin_amdgcn_perm(pv7, pv6, 0x07060302u);
        DOT8(r0, r1, dA);
        DOT8(r2, r3, dB);
        DOT8(r4, r5, dC);
        DOT8(r6, r7, dD);
    }
    for (; e + 2 <= e1; e += 2) {
        unsigned pv0 = esrc[e], pv1 = esrc[e + 1];
        uint4 r0 = hg4[(pv0 & 0xffffu) + cl];
        uint4 r1 = hg4[(pv1 & 0xffffu) + cl];
        unsigned dA = __builtin_amdgcn_perm(pv1, pv0, 0x07060302u);
        DOT8(r0, r1, dA);
    }
    if (e < e1) {
        unsigned pv = esrc[e];
        uint4 r = hg4[(pv & 0xffffu) + cl];
        unsigned dA = pv >> 16;            // (dv, 0)
        DOT8(r, r, dA);
    }
    // epilogue (all lanes; no shuffles)
    float di = dinv[wid];
    float sw = 2.0f * di * di;
    U8 hv; hv.u = hg4[nlc * 16 + cl];
    int cl8 = cl * 8;
    const float* bb = (cl8 < 64) ? &ba[cl8] : &bx[cl8 - 64];
    union { __half2 h2[4]; uint4 q; } pk;
    #pragma unroll
    for (int k = 0; k < 4; k++) {
        float ox = fmaxf(di * acc[2 * k]     + sw * __half2float(hv.h[2 * k])     + bb[2 * k],     0.0f);
        float oy = fmaxf(di * acc[2 * k + 1] + sw * __half2float(hv.h[2 * k + 1]) + bb[2 * k + 1], 0.0f);
        pk.h2[k] = __floats2half2_rn(ox, oy);
    }
    if (valid)
        *(uint4*)&outB16[(size_t)wid * 128 + cl8] = pk.q;
}

// ---------------- Aggregation, 64 channels (layer 2) + col-max partials ----------------
// R20 structure: 8-lane group = 1 node (uint4 row of 8), 32 nodes/block.
// R25: emits per-block col maxes (cols 0..31, LDS atomicMax) -> pmax.

__global__ __launch_bounds__(256) void k_agg64(const unsigned short* __restrict__ g16,
                                               const int* __restrict__ rowptr,
                                               const unsigned int* __restrict__ esrc,
                                               const float* __restrict__ dinv,
                                               const float* __restrict__ ba2,
                                               const float* __restrict__ bx2,
                                               float* __restrict__ s2,
                                               float* __restrict__ pmax) {
    __shared__ unsigned pm[32];
    int xcd = blockIdx.x & 7, slot = blockIdx.x >> 3;
    int gi = slot >> 5, chunk = slot & 31;        // 32 chunks x 32 nodes
    int g = xcd + 8 * gi;
    if (g >= NB) return;
    int t = threadIdx.x;
    if (t < 32) pm[t] = 0u;
    __syncthreads();
    int grp = t >> 3;              // node within block 0..31
    int cl  = t & 7;               // uint4 channel group
    int nl  = chunk * 32 + grp;
    int valid = nl < NPG;
    int nlc = valid ? nl : NPG - 1;
    int wid = g * NPG + nlc;
    const uint4* gg4 = (const uint4*)(g16 + (size_t)g * NPG * 64);
    float acc[8] = {};
    union U8 { uint4 u; __half h[8]; };
    int e0 = rowptr[wid];
    int e1 = valid ? rowptr[wid + 1] : e0;
    int e = e0;
    for (; e + 8 <= e1; e += 8) {
        unsigned pv0 = esrc[e + 0], pv1 = esrc[e + 1];
        unsigned pv2 = esrc[e + 2], pv3 = esrc[e + 3];
        unsigned pv4 = esrc[e + 4], pv5 = esrc[e + 5];
        unsigned pv6 = esrc[e + 6], pv7 = esrc[e + 7];
        uint4 r0 = gg4[((pv0 & 0xffffu) >> 1) + cl];
        uint4 r1 = gg4[((pv1 & 0xffffu) >> 1) + cl];
        uint4 r2 = gg4[((pv2 & 0xffffu) >> 1) + cl];
        uint4 r3 = gg4[((pv3 & 0xffffu) >> 1) + cl];
        uint4 r4 = gg4[((pv4 & 0xffffu) >> 1) + cl];
        uint4 r5 = gg4[((pv5 & 0xffffu) >> 1) + cl];
        uint4 r6 = gg4[((pv6 & 0xffffu) >> 1) + cl];
        uint4 r7 = gg4[((pv7 & 0xffffu) >> 1) + cl];
        unsigned dA = __builtin_amdgcn_perm(pv1, pv0, 0x07060302u);
        unsigned dB = __builtin_amdgcn_perm(pv3, pv2, 0x07060302u);
        unsigned dC = __builtin_amdgcn_perm(pv5, pv4, 0x07060302u);
        unsigned dD = __builtin_amdgcn_perm(pv7, pv6, 0x07060302u);
        DOT8(r0, r1, dA);
        DOT8(r2, r3, dB);
        DOT8(r4, r5, dC);
        DOT8(r6, r7, dD);
    }
    for (; e + 2 <= e1; e += 2) {
        unsigned pv0 = esrc[e], pv1 = esrc[e + 1];
        uint4 r0 = gg4[((pv0 & 0xffffu) >> 1) + cl];
        uint4 r1 = gg4[((pv1 & 0xffffu) >> 1) + cl];
        unsigned dA = __builtin_amdgcn_perm(pv1, pv0, 0x07060302u);
        DOT8(r0, r1, dA);
    }
    if (e < e1) {
        unsigned pv = esrc[e];
        uint4 r = gg4[((pv & 0xffffu) >> 1) + cl];
        unsigned dA = pv >> 16;
        DOT8(r, r, dA);
    }
    float di = dinv[wid];
    float sw = 2.0f * di * di;
    U8 hv; hv.u = gg4[nlc * 8 + cl];
    int cl8 = cl * 8;
    float o[8];
    #pragma unroll
    for (int k = 0; k < 8; k++)
        o[k] = di * acc[k] + sw * __half2float(hv.h[k]);
    if (cl8 < 32) {
        #pragma unroll
        for (int k = 0; k < 8; k++) o[k] += ba2[cl8 + k];
    } else {
        #pragma unroll
        for (int k = 0; k < 8; k++) o[k] = fmaxf(o[k] + bx2[cl8 - 32 + k], 0.0f);
    }
    if (valid) {
        *(float4*)&s2[(size_t)wid * 64 + cl8]     = make_float4(o[0], o[1], o[2], o[3]);
        *(float4*)&s2[(size_t)wid * 64 + cl8 + 4] = make_float4(o[4], o[5], o[6], o[7]);
    }
    if (valid && cl < 4) {
        #pragma unroll
        for (int k = 0; k < 8; k++)
            atomicMax(&pm[cl8 + k], fenc(o[k]));
    }
    __syncthreads();
    if (t < 32)
        pmax[((size_t)g * 32 + chunk) * 32 + t] = fdec(pm[t]);
}

// ---------------- GEMM 2 (MFMA): g16 = fp16( b16 @ Wpad[128][64] ) ----------------
// Wpad = [[Wa2; 0], [0; Wx2]] (block-diag padded to K=128), fp16 in LDS
// transposed [c][k] with the gemm1 XOR swizzle. Inputs b16 already fp16.

__global__ __launch_bounds__(256) void k_gemm2(const unsigned short* __restrict__ Bm16,
                                               const float* __restrict__ Wa2,
                                               const float* __restrict__ Wx2,
                                               unsigned short* __restrict__ g16) {
    __shared__ __align__(16) unsigned short wt2[8192];   // 64 cols x 128 k, 16KB
    int xcd = blockIdx.x & 7, slot = blockIdx.x >> 3;
    int g = xcd + 8 * (slot >> 4);
    int chunk = slot & 15;
    if (g >= NB) return;
    int row0 = g * NPG + chunk * 64;   // chunk 15 spills into next graph: benign dup
    int t = threadIdx.x;
    {
        int cc = t & 63, kg = t >> 6;          // kg 0..3 -> k block of 32
        #pragma unroll
        for (int j = 0; j < 8; j++) {
            int k0 = kg * 32 + j * 4;
            union { __half h[4]; uint2 u; } pk;
            #pragma unroll
            for (int m = 0; m < 4; m++) {
                int k = k0 + m;
                float v;
                if (cc < 32) v = (k < 64)  ? Wa2[k * 32 + cc] : 0.0f;
                else         v = (k >= 64) ? Wx2[(k - 64) * 32 + (cc - 32)] : 0.0f;
                pk.h[m] = __float2half_rn(v);
            }
            int byte = cc * 256 + ((2 * k0) ^ ((cc & 7) << 4));
            *(uint2*)((char*)wt2 + byte) = pk.u;
        }
    }
    __syncthreads();
    int w = t >> 6, l = t & 63;
    int lr = l & 15, kq = l >> 4;
    int rowA = row0 + w * 16 + lr;
    int rA = rowA < N_NODES ? rowA : N_NODES - 1;
    const unsigned short* xr = &Bm16[(size_t)rA * 128];
    h8_t a[4];
    #pragma unroll
    for (int kc = 0; kc < 4; kc++)
        a[kc] = *(const h8_t*)&xr[kc * 32 + kq * 8];
    f4_t acc[4] = {};
    #pragma unroll
    for (int kc = 0; kc < 4; kc++) {
        #pragma unroll
        for (int n = 0; n < 4; n++) {
            int cc = n * 16 + lr;
            int byte = cc * 256 + (((kc * 32 + kq * 8) * 2) ^ ((cc & 7) << 4));
            h8_t bf = *(h8_t*)((char*)wt2 + byte);
            acc[n] = __builtin_amdgcn_mfma_f32_16x16x32_f16(a[kc], bf, acc[n], 0, 0, 0);
        }
    }
    int rowD = row0 + w * 16 + kq * 4;
    #pragma unroll
    for (int n = 0; n < 4; n++) {
        #pragma unroll
        for (int j = 0; j < 4; j++) {
            int r = rowD + j;
            if (r < N_NODES)
                g16[(size_t)r * 64 + n * 16 + lr] =
                    __half_as_ushort(__float2half_rn(acc[n][j]));
        }
    }
}

// ---------------- Bilinear pool: 8 chunks/graph; reduces pmax, emits psum ----------------

__global__ __launch_bounds__(256) void k_pool(const float* __restrict__ s2,
                                              const float* __restrict__ pmax,
                                              float* __restrict__ psum,
                                              float* __restrict__ prods) {
    __shared__ float ta[25][32];
    __shared__ float tx[25][32];
    __shared__ float gm[32];
    int xcd = blockIdx.x & 7, slot = blockIdx.x >> 3;
    int g = xcd + 8 * (slot >> 3);
    int ch = slot & 7;
    if (g >= NB) return;
    int t = threadIdx.x;
    if (t < 32) {
        float m = -1e30f;
        for (int j = 0; j < 32; j++)
            m = fmaxf(m, pmax[((size_t)g * 32 + j) * 32 + t]);
        gm[t] = m;
    }
    int e  = t >> 3;
    int f4 = t & 7;
    float a0 = 0.f, a1 = 0.f, a2 = 0.f, a3 = 0.f;
    float csum = 0.f;
    int base = g * NPG + ch * 125;
    for (int n0 = 0; n0 < 125; n0 += 25) {
        __syncthreads();
        for (int i = t; i < 25 * 16; i += 256) {
            int r = i >> 4, c4 = i & 15;
            float4 v = *(const float4*)&s2[(size_t)(base + n0 + r) * 64 + c4 * 4];
            if (c4 < 8) {
                int cb = c4 * 4;
                v.x = __expf(v.x - gm[cb + 0]);
                v.y = __expf(v.y - gm[cb + 1]);
                v.z = __expf(v.z - gm[cb + 2]);
                v.w = __expf(v.w - gm[cb + 3]);
                *(float4*)&ta[r][cb] = v;
            } else {
                *(float4*)&tx[r][(c4 - 8) * 4] = v;
            }
        }
        __syncthreads();
        if (t < 32) {
            #pragma unroll 5
            for (int r = 0; r < 25; r++) csum += ta[r][t];
        }
        #pragma unroll 5
        for (int n = 0; n < 25; n++) {
            float a   = ta[n][e];
            float4 xv = *(float4*)&tx[n][f4 * 4];
            a0 += a * xv.x; a1 += a * xv.y; a2 += a * xv.z; a3 += a * xv.w;
        }
    }
    if (t < 32)
        psum[((size_t)g * 8 + ch) * 32 + t] = csum;
    *(float4*)&prods[((size_t)(g * 8 + ch)) * 1024 + e * 32 + f4 * 4] =
        make_float4(a0, a1, a2, a3);
}

// ---------------- Head: fold psum -> 1/s, sum 8 chunk-partials, linear, softmax ----------------

__global__ __launch_bounds__(256) void k_head(const float* __restrict__ prods,
                                              const float* __restrict__ psum,
                                              const float* __restrict__ Wlin,
                                              const float* __restrict__ blin,
                                              float* __restrict__ out) {
    __shared__ float red[4][NCLS];
    __shared__ float sinvv[32];
    int g = (blockIdx.x & 7) + 8 * (blockIdx.x >> 3);
    if (g >= NB) return;
    int t = threadIdx.x;
    if (t < 32) {
        float s = 0.f;
        for (int q = 0; q < 8; q++) s += psum[((size_t)g * 8 + q) * 32 + t];
        sinvv[t] = 1.0f / s;
    }
    __syncthreads();
    float p[NCLS];
    for (int c = 0; c < NCLS; c++) p[c] = 0.0f;
    const float* pg = &prods[(size_t)g * 8 * 1024];
    for (int j = 0; j < 4; j++) {
        int k = t * 4 + j;
        int e = k >> 5;
        float v = 0.0f;
        #pragma unroll
        for (int q = 0; q < 8; q++) v += pg[q * 1024 + k];
        v *= sinvv[e];
        const float* wrow = &Wlin[k * NCLS];
        for (int c = 0; c < NCLS; c++) p[c] += v * wrow[c];
    }
    for (int off = 32; off > 0; off >>= 1)
        for (int c = 0; c < NCLS; c++) p[c] += __shfl_down(p[c], off, 64);
    int wave = t >> 6, lane = t & 63;
    if (lane == 0)
        for (int c = 0; c < NCLS; c++) red[wave][c] = p[c];
    __syncthreads();
    if (t == 0) {
        float logits[NCLS]; float mx = -1e30f;
        for (int c = 0; c < NCLS; c++) {
            logits[c] = red[0][c] + red[1][c] + red[2][c] + red[3][c] + blin[c];
            mx = fmaxf(mx, logits[c]);
        }
        float s = 0.0f;
        for (int c = 0; c < NCLS; c++) { logits[c] = expf(logits[c] - mx); s += logits[c]; }
        float inv = 1.0f / s;
        for (int c = 0; c < NCLS; c++) out[g * NCLS + c] = logits[c] * inv;
    }
}

// ---------------- launch ----------------

extern "C" void kernel_launch(void* const* d_in, const int* in_sizes, int n_in,
                              void* d_out, int out_size, void* d_ws, size_t ws_size,
                              hipStream_t stream) {
    const float* x    = (const float*)d_in[0];
    const int*   ei   = (const int*)d_in[1];
    const float* Wa1  = (const float*)d_in[3];
    const float* ba1  = (const float*)d_in[4];
    const float* Wa2  = (const float*)d_in[5];
    const float* ba2  = (const float*)d_in[6];
    const float* Wx1  = (const float*)d_in[7];
    const float* bx1  = (const float*)d_in[8];
    const float* Wx2  = (const float*)d_in[9];
    const float* bx2  = (const float*)d_in[10];
    const float* Wlin = (const float*)d_in[11];
    const float* blin = (const float*)d_in[12];
    float* out = (float*)d_out;

    char* w = (char*)d_ws;
    auto alloc = [&](size_t bytes) -> void* {
        void* p = (void*)w;
        w += (bytes + 255) & ~(size_t)255;
        return p;
    };
    int*            rowptr = (int*)alloc((N_NODES + 1) * sizeof(int));
    int*            cnt8   = (int*)alloc((size_t)8 * N_NODES * sizeof(int));
    float*          dinv   = (float*)alloc(N_NODES * sizeof(float));
    unsigned short* dh16   = (unsigned short*)alloc(N_NODES * sizeof(unsigned short));
    unsigned int*   esrc   = (unsigned int*)alloc((size_t)N_EDGES * sizeof(unsigned int));
    float*          pmax   = (float*)alloc((size_t)NB * 32 * 32 * sizeof(float));
    float*          psum   = (float*)alloc((size_t)NB * 8 * 32 * sizeof(float));
    float*          prods  = (float*)alloc((size_t)NB * 8 * 1024 * sizeof(float));
    unsigned short* h16    = (unsigned short*)alloc((size_t)N_NODES * 128 * sizeof(unsigned short));
    unsigned short* b16    = (unsigned short*)alloc((size_t)N_NODES * 128 * sizeof(unsigned short));
    unsigned short* g16    = (unsigned short*)alloc((size_t)N_NODES * 64 * sizeof(unsigned short));
    float*          s2     = (float*)alloc((size_t)N_NODES * 64 * sizeof(float));

    const int* srcp = ei;
    const int* dstp = ei + N_EDGES;

    k_cnt<<<CNT_BLOCKS, 256, 0, stream>>>(dstp, cnt8);
    k_scan<<<8 * 13, 1024, 0, stream>>>(cnt8, rowptr, dinv, dh16);
    k_sg<<<SORT_BLOCKS + 8 * 13 * 4, 1024, 0, stream>>>(srcp, dstp, x, Wa1, Wx1,
                                                        rowptr, dh16, esrc, h16);
    k_agg128<<<8 * 13 * 63, 256, 0, stream>>>(h16, rowptr, esrc, dinv, ba1, bx1, b16);
    k_gemm2<<<8 * 13 * 16, 256, 0, stream>>>(b16, Wa2, Wx2, g16);
    k_agg64<<<8 * 13 * 32, 256, 0, stream>>>(g16, rowptr, esrc, dinv, ba2, bx2, s2, pmax);
    k_pool<<<8 * 13 * 8, 256, 0, stream>>>(s2, pmax, psum, prods);
    k_head<<<8 * 13, 256, 0, stream>>>(prods, psum, Wlin, blin, out);
}

// Round 14
// 290.785 us; speedup vs baseline: 1.4926x; 1.0564x over previous
//
#include <hip/hip_runtime.h>
#include <hip/hip_bf16.h>
#include <hip/hip_fp16.h>

#define N_NODES 100000
#define N_EDGES 3200000
#define NB      100
#define NPG     1000
#define EPG     32000    // edges per graph
#define DIN     128
#define DH      64
#define DE      32
#define NCLS    10
#define CNT_BLOCKS  832  // 8 slices x 104
#define SORT_BLOCKS 416  // 4 node-quarters x 104 (R28's 8-way split REGRESSED:
                         // filtered scan cost scales with splits; FETCH 44->51MB)

// XCD-affine swizzle: graph g lives on XCD g%8. Aggregation = PULL gather
// from L2. R14: packed (src|fp16 dinv) edge recs. R16: MACs via
// v_dot2_f32_f16 (DOT8). R17: gemm1 on MFMA. R19: parallel CSR build.
// Agg history: R20 group-per-node straight 8-edge unroll = 56.5us BEST.
// R21 depth-8 pipeline FAILED (VGPR cliff). R22 LDS staging FAILED (occ).
// R23 channel-split NULL. R24 launch-bounds cap FAILED (scratch spills).
// R26/R27 dense-slab MFMA SpMM FAILED (serial owner-scatter, 15.9M bank
// conflicts). Aggregation CLOSED as L2-latency-bound gather at ~57us.
// R25 (proven 288.7us): gemm2 on MFMA; k_smax deleted (pmax/psum fusion).
// R29 = R25 + gemm2 FUSED into agg128's epilogue: relu'd fp16 row -> 4KB
// LDS tile bs[16][128] (gemm1's XOR swizzle), one sync, 4 MFMA/wave
// (bs @ Wpad[128x64], W staged per block) -> g16 direct. Deletes k_gemm2
// launch + 50MB b16 round-trip. Hot gather loop byte-identical to R25.

typedef _Float16 h2_t __attribute__((ext_vector_type(2)));
typedef _Float16 h8_t __attribute__((ext_vector_type(8)));
typedef float    f4_t __attribute__((ext_vector_type(4)));

__device__ __forceinline__ float dot2f(unsigned a, unsigned b, float c) {
#if __has_builtin(__builtin_amdgcn_fdot2)
    return __builtin_amdgcn_fdot2(__builtin_bit_cast(h2_t, a),
                                  __builtin_bit_cast(h2_t, b), c, false);
#else
    float d;
    asm("v_dot2_f32_f16 %0, %1, %2, %3" : "=v"(d) : "v"(a), "v"(b), "v"(c));
    return d;
#endif
}

// rA = edge A regs (halfs), rB = edge B, dv = half2(dvA, dvB).
// perm sel: src1 bytes are idx 0..3, src0 bytes idx 4..7.
#define DOT8(rA, rB, dv)                                                        \
    acc[0] = dot2f(__builtin_amdgcn_perm(rB.x, rA.x, 0x05040100u), dv, acc[0]); \
    acc[1] = dot2f(__builtin_amdgcn_perm(rB.x, rA.x, 0x07060302u), dv, acc[1]); \
    acc[2] = dot2f(__builtin_amdgcn_perm(rB.y, rA.y, 0x05040100u), dv, acc[2]); \
    acc[3] = dot2f(__builtin_amdgcn_perm(rB.y, rA.y, 0x07060302u), dv, acc[3]); \
    acc[4] = dot2f(__builtin_amdgcn_perm(rB.z, rA.z, 0x05040100u), dv, acc[4]); \
    acc[5] = dot2f(__builtin_amdgcn_perm(rB.z, rA.z, 0x07060302u), dv, acc[5]); \
    acc[6] = dot2f(__builtin_amdgcn_perm(rB.w, rA.w, 0x05040100u), dv, acc[6]); \
    acc[7] = dot2f(__builtin_amdgcn_perm(rB.w, rA.w, 0x07060302u), dv, acc[7]);

__device__ __forceinline__ unsigned fenc(float f) {
    unsigned u = __float_as_uint(f);
    return u ^ (unsigned)(((int)u >> 31) | (int)0x80000000);
}
__device__ __forceinline__ float fdec(unsigned key) {
    return (key & 0x80000000u) ? __uint_as_float(key ^ 0x80000000u)
                               : __uint_as_float(~key);
}

// ---------------- Phase 1: per-slice degree count ----------------

__global__ __launch_bounds__(256) void k_cnt(const int* __restrict__ dst,
                                             int* __restrict__ cnt8) {
    __shared__ int cnt[NPG];
    int slice = blockIdx.x >> 3;
    int g = (blockIdx.x & 7) + 8 * (slice % 13);
    int sub = slice / 13;                     // 0..7
    if (g >= NB) return;
    int t = threadIdx.x;
    for (int i = t; i < NPG; i += 256) cnt[i] = 0;
    __syncthreads();
    int ebase = g * EPG + sub * 4000, nbase = g * NPG;
    for (int i = t; i < 4000; i += 256)
        atomicAdd(&cnt[dst[ebase + i] - nbase], 1);
    __syncthreads();
    for (int i = t; i < NPG; i += 256)
        cnt8[sub * N_NODES + nbase + i] = cnt[i];
}

// ---------------- Phase 2: deg sum, scan -> rowptr, dinv/dh16 ----------------

__global__ __launch_bounds__(1024) void k_scan(const int* __restrict__ cnt8,
                                               int* __restrict__ rowptr,
                                               float* __restrict__ dinv,
                                               unsigned short* __restrict__ dh16) {
    __shared__ int sm[1024];
    int g = (blockIdx.x & 7) + 8 * (blockIdx.x >> 3);
    if (g >= NB) return;
    int t = threadIdx.x;
    int nbase = g * NPG, ebase = g * EPG;
    int v = 0;
    if (t < NPG) {
        #pragma unroll
        for (int s8 = 0; s8 < 8; s8++) v += cnt8[s8 * N_NODES + nbase + t];
        float dv = rsqrtf((float)v + 2.0f);
        dinv[nbase + t] = dv;
        dh16[nbase + t] = __half_as_ushort(__float2half_rn(dv));
    }
    sm[t] = v;
    __syncthreads();
    for (int off = 1; off < 1024; off <<= 1) {
        int xx = (t >= off) ? sm[t - off] : 0;
        __syncthreads();
        sm[t] += xx;
        __syncthreads();
    }
    if (t < NPG)
        rowptr[nbase + t] = ebase + sm[t] - v;
    if (g == NB - 1 && t == 0) rowptr[N_NODES] = N_EDGES;
}

// ---------------- Phase 3 fused: LDS-staged edge scatter + MFMA GEMM1 ----------------
// blocks [0,416): sort quarter (g,q). blocks [416,832): gemm1, 250 rows each.
// Edge record: uint32 = (src_local*16) | (fp16(dinv[src]) << 16).

union SharedSG {
    struct {
        int cur[256];                            // LDS cursors (local offsets)
        unsigned buf[10000];                     // staged records
    } sc;
    struct {
        __align__(16) unsigned short wt[16384];  // fp16 W^T [c][k], swizzled
    } ge;
};

__global__ __launch_bounds__(1024) void k_sg(const int* __restrict__ src,
                                             const int* __restrict__ dst,
                                             const float* __restrict__ x,
                                             const float* __restrict__ Wa,
                                             const float* __restrict__ Wx,
                                             const int* __restrict__ rowptr,
                                             const unsigned short* __restrict__ dh16,
                                             unsigned int* __restrict__ esrc,
                                             unsigned short* __restrict__ h16) {
    __shared__ SharedSG S;
    int t = threadIdx.x;
    if (blockIdx.x < SORT_BLOCKS) {
        // ---------------- scatter path ----------------
        int xcd = blockIdx.x & 7, slot = blockIdx.x >> 3;
        int g = xcd + 8 * (slot % 13);
        int q = slot / 13;                       // node quarter 0..3
        if (g >= NB) return;
        int nbase = g * NPG, ebase = g * EPG;
        int n0 = q * 250;
        int base0 = rowptr[nbase + n0];
        int cap = rowptr[nbase + n0 + 250] - base0;
        if (t < 250)
            S.sc.cur[t] = rowptr[nbase + n0 + t] - base0;
        __syncthreads();
        for (int i = t; i < EPG; i += 1024) {
            int d = dst[ebase + i] - nbase - n0;
            if ((unsigned)d < 250u) {
                int s = src[ebase + i];
                int pos = atomicAdd(&S.sc.cur[d], 1);
                S.sc.buf[pos] = ((unsigned)(s - nbase) * 16) |
                                ((unsigned)dh16[s] << 16);
            }
        }
        __syncthreads();
        for (int i = t; i < cap; i += 1024)
            esrc[base0 + i] = S.sc.buf[i];
    } else {
        // ------------- gemm1 path (MFMA): h16 = fp16( x @ [W_a1 | W_x1] ) -------------
        int b2 = blockIdx.x - SORT_BLOCKS;         // 8*13*4 blocks
        int xcd = b2 & 7, slot = b2 >> 3;
        int g = xcd + 8 * (slot >> 2);
        int chunk = slot & 3;                       // 4 x 250-row chunks/graph
        if (g >= NB) return;
        int row0 = g * NPG + chunk * 250;
        // stage W^T fp16 in LDS, layout [c][k], byte ^= (c&7)<<4.
        {
            int cc = t & 127, kg = t >> 7;          // kg 0..7 -> k block of 16
            const float* Wp = (cc < 64) ? &Wa[cc] : &Wx[cc - 64];
            #pragma unroll
            for (int j = 0; j < 4; j++) {
                int k0 = kg * 16 + j * 4;
                union { __half h[4]; uint2 u; } pk;
                #pragma unroll
                for (int m = 0; m < 4; m++)
                    pk.h[m] = __float2half_rn(Wp[(k0 + m) * 64]);
                int byte = cc * 256 + ((2 * k0) ^ ((cc & 7) << 4));
                *(uint2*)((char*)S.ge.wt + byte) = pk.u;
            }
        }
        __syncthreads();
        int w = t >> 6, l = t & 63;
        int lr = l & 15, kq = l >> 4;               // A/B row|col, k-quarter
        int rowA = row0 + w * 16 + lr;
        int rA = rowA < N_NODES ? rowA : N_NODES - 1;
        const float* xr = &x[(size_t)rA * 128];
        h8_t a[4];
        #pragma unroll
        for (int kc = 0; kc < 4; kc++) {
            float4 lo = *(const float4*)&xr[kc * 32 + kq * 8];
            float4 hi = *(const float4*)&xr[kc * 32 + kq * 8 + 4];
            h8_t av;
            av[0] = (_Float16)lo.x; av[1] = (_Float16)lo.y;
            av[2] = (_Float16)lo.z; av[3] = (_Float16)lo.w;
            av[4] = (_Float16)hi.x; av[5] = (_Float16)hi.y;
            av[6] = (_Float16)hi.z; av[7] = (_Float16)hi.w;
            a[kc] = av;
        }
        f4_t acc[8] = {};
        #pragma unroll
        for (int kc = 0; kc < 4; kc++) {
            #pragma unroll
            for (int n = 0; n < 8; n++) {
                int cc = n * 16 + lr;
                int byte = cc * 256 + (((kc * 32 + kq * 8) * 2) ^ ((cc & 7) << 4));
                h8_t bf = *(h8_t*)((char*)S.ge.wt + byte);
                acc[n] = __builtin_amdgcn_mfma_f32_16x16x32_f16(a[kc], bf, acc[n], 0, 0, 0);
            }
        }
        // D: col = lane&15 (=lr), row = 4*kq + reg
        int rowD = row0 + w * 16 + kq * 4;
        #pragma unroll
        for (int n = 0; n < 8; n++) {
            #pragma unroll
            for (int j = 0; j < 4; j++) {
                int r = rowD + j;
                if (r < N_NODES)
                    h16[(size_t)r * 128 + n * 16 + lr] =
                        __half_as_ushort(__float2half_rn(acc[n][j]));
            }
        }
    }
}

// ---------------- Aggregation 128ch (layer 1) + FUSED gemm2 ----------------
// Hot loop = R20/R25 proven structure (16-lane group = 1 node, lane owns
// 8 ch, straight 8-edge unroll). Epilogue: relu'd fp16 row -> LDS bs
// (swizzled), one sync, 4 MFMA/wave: g16 = bs[16x128] @ Wpad[128x64].

__global__ __launch_bounds__(256) void k_agg128(const unsigned short* __restrict__ h16,
                                                const int* __restrict__ rowptr,
                                                const unsigned int* __restrict__ esrc,
                                                const float* __restrict__ dinv,
                                                const float* __restrict__ ba,
                                                const float* __restrict__ bx,
                                                const float* __restrict__ Wa2,
                                                const float* __restrict__ Wx2,
                                                unsigned short* __restrict__ g16) {
    __shared__ __align__(16) unsigned short wt2[8192];   // Wpad^T [c][k] swizzled, 16KB
    __shared__ __align__(16) unsigned short bs[2048];    // 16 nodes x 128 ch, 4KB
    int xcd = blockIdx.x & 7, slot = blockIdx.x >> 3;
    int gi = slot / 63, chunk = slot - gi * 63;   // 63 chunks x 16 nodes
    int g = xcd + 8 * gi;
    if (g >= NB) return;
    int t = threadIdx.x;
    {   // stage Wpad = [[Wa2;0],[0;Wx2]] fp16 [c][k], byte ^= (c&7)<<4 (gemm2 verbatim)
        int cc = t & 63, kg = t >> 6;          // kg 0..3 -> k block of 32
        #pragma unroll
        for (int j = 0; j < 8; j++) {
            int k0 = kg * 32 + j * 4;
            union { __half h[4]; uint2 u; } pk;
            #pragma unroll
            for (int m = 0; m < 4; m++) {
                int k = k0 + m;
                float v;
                if (cc < 32) v = (k < 64)  ? Wa2[k * 32 + cc] : 0.0f;
                else         v = (k >= 64) ? Wx2[(k - 64) * 32 + (cc - 32)] : 0.0f;
                pk.h[m] = __float2half_rn(v);
            }
            int byte = cc * 256 + ((2 * k0) ^ ((cc & 7) << 4));
            *(uint2*)((char*)wt2 + byte) = pk.u;
        }
    }
    int grp = t >> 4;    // node within block 0..15
    int cl  = t & 15;    // uint4 channel group
    int nl  = chunk * 16 + grp;
    int valid = nl < NPG;
    int nlc = valid ? nl : NPG - 1;
    int wid = g * NPG + nlc;
    const uint4* hg4 = (const uint4*)(h16 + (size_t)g * NPG * 128);
    float acc[8] = {};
    union U8 { uint4 u; __half h[8]; };
    int e0 = rowptr[wid];
    int e1 = valid ? rowptr[wid + 1] : e0;
    int e = e0;
    for (; e + 8 <= e1; e += 8) {
        unsigned pv0 = esrc[e + 0], pv1 = esrc[e + 1];
        unsigned pv2 = esrc[e + 2], pv3 = esrc[e + 3];
        unsigned pv4 = esrc[e + 4], pv5 = esrc[e + 5];
        unsigned pv6 = esrc[e + 6], pv7 = esrc[e + 7];
        uint4 r0 = hg4[(pv0 & 0xffffu) + cl];
        uint4 r1 = hg4[(pv1 & 0xffffu) + cl];
        uint4 r2 = hg4[(pv2 & 0xffffu) + cl];
        uint4 r3 = hg4[(pv3 & 0xffffu) + cl];
        uint4 r4 = hg4[(pv4 & 0xffffu) + cl];
        uint4 r5 = hg4[(pv5 & 0xffffu) + cl];
        uint4 r6 = hg4[(pv6 & 0xffffu) + cl];
        uint4 r7 = hg4[(pv7 & 0xffffu) + cl];
        unsigned dA = __builtin_amdgcn_perm(pv1, pv0, 0x07060302u);
        unsigned dB = __builtin_amdgcn_perm(pv3, pv2, 0x07060302u);
        unsigned dC = __builtin_amdgcn_perm(pv5, pv4, 0x07060302u);
        unsigned dD = __builtin_amdgcn_perm(pv7, pv6, 0x07060302u);
        DOT8(r0, r1, dA);
        DOT8(r2, r3, dB);
        DOT8(r4, r5, dC);
        DOT8(r6, r7, dD);
    }
    for (; e + 2 <= e1; e += 2) {
        unsigned pv0 = esrc[e], pv1 = esrc[e + 1];
        uint4 r0 = hg4[(pv0 & 0xffffu) + cl];
        uint4 r1 = hg4[(pv1 & 0xffffu) + cl];
        unsigned dA = __builtin_amdgcn_perm(pv1, pv0, 0x07060302u);
        DOT8(r0, r1, dA);
    }
    if (e < e1) {
        unsigned pv = esrc[e];
        uint4 r = hg4[(pv & 0xffffu) + cl];
        unsigned dA = pv >> 16;            // (dv, 0)
        DOT8(r, r, dA);
    }
    // epilogue: relu'd fp16 row into LDS bs (zero for invalid rows)
    {
        float di = dinv[wid];
        float sw = 2.0f * di * di;
        U8 hv; hv.u = hg4[nlc * 16 + cl];
        int cl8 = cl * 8;
        const float* bb = (cl8 < 64) ? &ba[cl8] : &bx[cl8 - 64];
        union { __half h[8]; uint4 q; } pk;
        #pragma unroll
        for (int k = 0; k < 8; k++) {
            float o = fmaxf(di * acc[k] + sw * __half2float(hv.h[k]) + bb[k], 0.0f);
            pk.h[k] = valid ? __float2half_rn(o) : __float2half_rn(0.0f);
        }
        *(uint4*)((char*)bs + grp * 256 + ((cl * 16) ^ ((grp & 7) << 4))) = pk.q;
    }
    __syncthreads();
    // fused gemm2: wave w computes col-tile w (16 cols); rows = 16 nodes
    {
        int w = t >> 6, l = t & 63;
        int lr = l & 15, kq = l >> 4;
        f4_t acc2 = {0.0f, 0.0f, 0.0f, 0.0f};
        #pragma unroll
        for (int kc = 0; kc < 4; kc++) {
            int kb = (kc * 32 + kq * 8) * 2;
            h8_t a = *(h8_t*)((char*)bs + lr * 256 + (kb ^ ((lr & 7) << 4)));
            int cc = w * 16 + lr;
            h8_t bfr = *(h8_t*)((char*)wt2 + cc * 256 + (kb ^ ((cc & 7) << 4)));
            acc2 = __builtin_amdgcn_mfma_f32_16x16x32_f16(a, bfr, acc2, 0, 0, 0);
        }
        // D: col = w*16+lr, row (block-local node) = 4*kq + j
        #pragma unroll
        for (int j = 0; j < 4; j++) {
            int nl2 = chunk * 16 + 4 * kq + j;
            if (nl2 < NPG)
                g16[((size_t)(g * NPG + nl2)) * 64 + w * 16 + lr] =
                    __half_as_ushort(__float2half_rn(acc2[j]));
        }
    }
}

// ---------------- Aggregation, 64 channels (layer 2) + col-max partials ----------------
// R20 structure: 8-lane group = 1 node (uint4 row of 8), 32 nodes/block.
// R25: emits per-block col maxes (cols 0..31, LDS atomicMax) -> pmax.

__global__ __launch_bounds__(256) void k_agg64(const unsigned short* __restrict__ g16,
                                               const int* __restrict__ rowptr,
                                               const unsigned int* __restrict__ esrc,
                                               const float* __restrict__ dinv,
                                               const float* __restrict__ ba2,
                                               const float* __restrict__ bx2,
                                               float* __restrict__ s2,
                                               float* __restrict__ pmax) {
    __shared__ unsigned pm[32];
    int xcd = blockIdx.x & 7, slot = blockIdx.x >> 3;
    int gi = slot >> 5, chunk = slot & 31;        // 32 chunks x 32 nodes
    int g = xcd + 8 * gi;
    if (g >= NB) return;
    int t = threadIdx.x;
    if (t < 32) pm[t] = 0u;
    __syncthreads();
    int grp = t >> 3;              // node within block 0..31
    int cl  = t & 7;               // uint4 channel group
    int nl  = chunk * 32 + grp;
    int valid = nl < NPG;
    int nlc = valid ? nl : NPG - 1;
    int wid = g * NPG + nlc;
    const uint4* gg4 = (const uint4*)(g16 + (size_t)g * NPG * 64);
    float acc[8] = {};
    union U8 { uint4 u; __half h[8]; };
    int e0 = rowptr[wid];
    int e1 = valid ? rowptr[wid + 1] : e0;
    int e = e0;
    for (; e + 8 <= e1; e += 8) {
        unsigned pv0 = esrc[e + 0], pv1 = esrc[e + 1];
        unsigned pv2 = esrc[e + 2], pv3 = esrc[e + 3];
        unsigned pv4 = esrc[e + 4], pv5 = esrc[e + 5];
        unsigned pv6 = esrc[e + 6], pv7 = esrc[e + 7];
        uint4 r0 = gg4[((pv0 & 0xffffu) >> 1) + cl];
        uint4 r1 = gg4[((pv1 & 0xffffu) >> 1) + cl];
        uint4 r2 = gg4[((pv2 & 0xffffu) >> 1) + cl];
        uint4 r3 = gg4[((pv3 & 0xffffu) >> 1) + cl];
        uint4 r4 = gg4[((pv4 & 0xffffu) >> 1) + cl];
        uint4 r5 = gg4[((pv5 & 0xffffu) >> 1) + cl];
        uint4 r6 = gg4[((pv6 & 0xffffu) >> 1) + cl];
        uint4 r7 = gg4[((pv7 & 0xffffu) >> 1) + cl];
        unsigned dA = __builtin_amdgcn_perm(pv1, pv0, 0x07060302u);
        unsigned dB = __builtin_amdgcn_perm(pv3, pv2, 0x07060302u);
        unsigned dC = __builtin_amdgcn_perm(pv5, pv4, 0x07060302u);
        unsigned dD = __builtin_amdgcn_perm(pv7, pv6, 0x07060302u);
        DOT8(r0, r1, dA);
        DOT8(r2, r3, dB);
        DOT8(r4, r5, dC);
        DOT8(r6, r7, dD);
    }
    for (; e + 2 <= e1; e += 2) {
        unsigned pv0 = esrc[e], pv1 = esrc[e + 1];
        uint4 r0 = gg4[((pv0 & 0xffffu) >> 1) + cl];
        uint4 r1 = gg4[((pv1 & 0xffffu) >> 1) + cl];
        unsigned dA = __builtin_amdgcn_perm(pv1, pv0, 0x07060302u);
        DOT8(r0, r1, dA);
    }
    if (e < e1) {
        unsigned pv = esrc[e];
        uint4 r = gg4[((pv & 0xffffu) >> 1) + cl];
        unsigned dA = pv >> 16;
        DOT8(r, r, dA);
    }
    float di = dinv[wid];
    float sw = 2.0f * di * di;
    U8 hv; hv.u = gg4[nlc * 8 + cl];
    int cl8 = cl * 8;
    float o[8];
    #pragma unroll
    for (int k = 0; k < 8; k++)
        o[k] = di * acc[k] + sw * __half2float(hv.h[k]);
    if (cl8 < 32) {
        #pragma unroll
        for (int k = 0; k < 8; k++) o[k] += ba2[cl8 + k];
    } else {
        #pragma unroll
        for (int k = 0; k < 8; k++) o[k] = fmaxf(o[k] + bx2[cl8 - 32 + k], 0.0f);
    }
    if (valid) {
        *(float4*)&s2[(size_t)wid * 64 + cl8]     = make_float4(o[0], o[1], o[2], o[3]);
        *(float4*)&s2[(size_t)wid * 64 + cl8 + 4] = make_float4(o[4], o[5], o[6], o[7]);
    }
    if (valid && cl < 4) {
        #pragma unroll
        for (int k = 0; k < 8; k++)
            atomicMax(&pm[cl8 + k], fenc(o[k]));
    }
    __syncthreads();
    if (t < 32)
        pmax[((size_t)g * 32 + chunk) * 32 + t] = fdec(pm[t]);
}

// ---------------- Bilinear pool: 8 chunks/graph; reduces pmax, emits psum ----------------

__global__ __launch_bounds__(256) void k_pool(const float* __restrict__ s2,
                                              const float* __restrict__ pmax,
                                              float* __restrict__ psum,
                                              float* __restrict__ prods) {
    __shared__ float ta[25][32];
    __shared__ float tx[25][32];
    __shared__ float gm[32];
    int xcd = blockIdx.x & 7, slot = blockIdx.x >> 3;
    int g = xcd + 8 * (slot >> 3);
    int ch = slot & 7;
    if (g >= NB) return;
    int t = threadIdx.x;
    if (t < 32) {
        float m = -1e30f;
        for (int j = 0; j < 32; j++)
            m = fmaxf(m, pmax[((size_t)g * 32 + j) * 32 + t]);
        gm[t] = m;
    }
    int e  = t >> 3;
    int f4 = t & 7;
    float a0 = 0.f, a1 = 0.f, a2 = 0.f, a3 = 0.f;
    float csum = 0.f;
    int base = g * NPG + ch * 125;
    for (int n0 = 0; n0 < 125; n0 += 25) {
        __syncthreads();
        for (int i = t; i < 25 * 16; i += 256) {
            int r = i >> 4, c4 = i & 15;
            float4 v = *(const float4*)&s2[(size_t)(base + n0 + r) * 64 + c4 * 4];
            if (c4 < 8) {
                int cb = c4 * 4;
                v.x = __expf(v.x - gm[cb + 0]);
                v.y = __expf(v.y - gm[cb + 1]);
                v.z = __expf(v.z - gm[cb + 2]);
                v.w = __expf(v.w - gm[cb + 3]);
                *(float4*)&ta[r][cb] = v;
            } else {
                *(float4*)&tx[r][(c4 - 8) * 4] = v;
            }
        }
        __syncthreads();
        if (t < 32) {
            #pragma unroll 5
            for (int r = 0; r < 25; r++) csum += ta[r][t];
        }
        #pragma unroll 5
        for (int n = 0; n < 25; n++) {
            float a   = ta[n][e];
            float4 xv = *(float4*)&tx[n][f4 * 4];
            a0 += a * xv.x; a1 += a * xv.y; a2 += a * xv.z; a3 += a * xv.w;
        }
    }
    if (t < 32)
        psum[((size_t)g * 8 + ch) * 32 + t] = csum;
    *(float4*)&prods[((size_t)(g * 8 + ch)) * 1024 + e * 32 + f4 * 4] =
        make_float4(a0, a1, a2, a3);
}

// ---------------- Head: fold psum -> 1/s, sum 8 chunk-partials, linear, softmax ----------------

__global__ __launch_bounds__(256) void k_head(const float* __restrict__ prods,
                                              const float* __restrict__ psum,
                                              const float* __restrict__ Wlin,
                                              const float* __restrict__ blin,
                                              float* __restrict__ out) {
    __shared__ float red[4][NCLS];
    __shared__ float sinvv[32];
    int g = (blockIdx.x & 7) + 8 * (blockIdx.x >> 3);
    if (g >= NB) return;
    int t = threadIdx.x;
    if (t < 32) {
        float s = 0.f;
        for (int q = 0; q < 8; q++) s += psum[((size_t)g * 8 + q) * 32 + t];
        sinvv[t] = 1.0f / s;
    }
    __syncthreads();
    float p[NCLS];
    for (int c = 0; c < NCLS; c++) p[c] = 0.0f;
    const float* pg = &prods[(size_t)g * 8 * 1024];
    for (int j = 0; j < 4; j++) {
        int k = t * 4 + j;
        int e = k >> 5;
        float v = 0.0f;
        #pragma unroll
        for (int q = 0; q < 8; q++) v += pg[q * 1024 + k];
        v *= sinvv[e];
        const float* wrow = &Wlin[k * NCLS];
        for (int c = 0; c < NCLS; c++) p[c] += v * wrow[c];
    }
    for (int off = 32; off > 0; off >>= 1)
        for (int c = 0; c < NCLS; c++) p[c] += __shfl_down(p[c], off, 64);
    int wave = t >> 6, lane = t & 63;
    if (lane == 0)
        for (int c = 0; c < NCLS; c++) red[wave][c] = p[c];
    __syncthreads();
    if (t == 0) {
        float logits[NCLS]; float mx = -1e30f;
        for (int c = 0; c < NCLS; c++) {
            logits[c] = red[0][c] + red[1][c] + red[2][c] + red[3][c] + blin[c];
            mx = fmaxf(mx, logits[c]);
        }
        float s = 0.0f;
        for (int c = 0; c < NCLS; c++) { logits[c] = expf(logits[c] - mx); s += logits[c]; }
        float inv = 1.0f / s;
        for (int c = 0; c < NCLS; c++) out[g * NCLS + c] = logits[c] * inv;
    }
}

// ---------------- launch ----------------

extern "C" void kernel_launch(void* const* d_in, const int* in_sizes, int n_in,
                              void* d_out, int out_size, void* d_ws, size_t ws_size,
                              hipStream_t stream) {
    const float* x    = (const float*)d_in[0];
    const int*   ei   = (const int*)d_in[1];
    const float* Wa1  = (const float*)d_in[3];
    const float* ba1  = (const float*)d_in[4];
    const float* Wa2  = (const float*)d_in[5];
    const float* ba2  = (const float*)d_in[6];
    const float* Wx1  = (const float*)d_in[7];
    const float* bx1  = (const float*)d_in[8];
    const float* Wx2  = (const float*)d_in[9];
    const float* bx2  = (const float*)d_in[10];
    const float* Wlin = (const float*)d_in[11];
    const float* blin = (const float*)d_in[12];
    float* out = (float*)d_out;

    char* w = (char*)d_ws;
    auto alloc = [&](size_t bytes) -> void* {
        void* p = (void*)w;
        w += (bytes + 255) & ~(size_t)255;
        return p;
    };
    int*            rowptr = (int*)alloc((N_NODES + 1) * sizeof(int));
    int*            cnt8   = (int*)alloc((size_t)8 * N_NODES * sizeof(int));
    float*          dinv   = (float*)alloc(N_NODES * sizeof(float));
    unsigned short* dh16   = (unsigned short*)alloc(N_NODES * sizeof(unsigned short));
    unsigned int*   esrc   = (unsigned int*)alloc((size_t)N_EDGES * sizeof(unsigned int));
    float*          pmax   = (float*)alloc((size_t)NB * 32 * 32 * sizeof(float));
    float*          psum   = (float*)alloc((size_t)NB * 8 * 32 * sizeof(float));
    float*          prods  = (float*)alloc((size_t)NB * 8 * 1024 * sizeof(float));
    unsigned short* h16    = (unsigned short*)alloc((size_t)N_NODES * 128 * sizeof(unsigned short));
    unsigned short* g16    = (unsigned short*)alloc((size_t)N_NODES * 64 * sizeof(unsigned short));
    float*          s2     = (float*)alloc((size_t)N_NODES * 64 * sizeof(float));

    const int* srcp = ei;
    const int* dstp = ei + N_EDGES;

    k_cnt<<<CNT_BLOCKS, 256, 0, stream>>>(dstp, cnt8);
    k_scan<<<8 * 13, 1024, 0, stream>>>(cnt8, rowptr, dinv, dh16);
    k_sg<<<SORT_BLOCKS + 8 * 13 * 4, 1024, 0, stream>>>(srcp, dstp, x, Wa1, Wx1,
                                                        rowptr, dh16, esrc, h16);
    k_agg128<<<8 * 13 * 63, 256, 0, stream>>>(h16, rowptr, esrc, dinv, ba1, bx1,
                                              Wa2, Wx2, g16);
    k_agg64<<<8 * 13 * 32, 256, 0, stream>>>(g16, rowptr, esrc, dinv, ba2, bx2, s2, pmax);
    k_pool<<<8 * 13 * 8, 256, 0, stream>>>(s2, pmax, psum, prods);
    k_head<<<8 * 13, 256, 0, stream>>>(prods, psum, Wlin, blin, out);
}

// Round 15
// 288.136 us; speedup vs baseline: 1.5064x; 1.0092x over previous
//
#include <hip/hip_runtime.h>
#include <hip/hip_bf16.h>
#include <hip/hip_fp16.h>

#define N_NODES 100000
#define N_EDGES 3200000
#define NB      100
#define NPG     1000
#define EPG     32000    // edges per graph
#define DIN     128
#define DH      64
#define DE      32
#define NCLS    10
#define CNT_BLOCKS  832  // 8 slices x 104
#define SORT_BLOCKS 416  // 4 node-quarters x 104

// FINAL (R30) = R25, the session's best measured config (288.7us).
// Techniques: XCD-affine swizzle (graph g on XCD g%8, working set in one
// 4MB L2); packed (src|fp16 dinv) edge records; v_dot2_f32_f16 edge-pair
// MACs (DOT8); gemm1+gemm2 on MFMA (v_mfma_f32_16x16x32_f16, fp16 W in LDS
// with XOR swizzle); 3-phase parallel CSR build (count -> scan -> LDS-staged
// scatter fused with gemm1); k_smax eliminated (agg64 emits per-chunk col
// maxes -> pmax; pool reduces pmax + emits exp-sums -> psum; head folds).
// Closed negatives (verified): deeper agg ILP (VGPR cliff / spills), LDS
// staging (occupancy), channel-split (no new concurrency), dense-slab MFMA
// SpMM (serial owner-scatter), 8-way sort split (filtered-scan refetch),
// gemm2-into-agg128 fusion (barrier load-imbalance ~ launch savings).
// Aggregation is L2-latency-bound at ~57us (6 experiments), HBM 10%,
// VALU 40% -- structural floor for this gather formulation.

typedef _Float16 h2_t __attribute__((ext_vector_type(2)));
typedef _Float16 h8_t __attribute__((ext_vector_type(8)));
typedef float    f4_t __attribute__((ext_vector_type(4)));

__device__ __forceinline__ float dot2f(unsigned a, unsigned b, float c) {
#if __has_builtin(__builtin_amdgcn_fdot2)
    return __builtin_amdgcn_fdot2(__builtin_bit_cast(h2_t, a),
                                  __builtin_bit_cast(h2_t, b), c, false);
#else
    float d;
    asm("v_dot2_f32_f16 %0, %1, %2, %3" : "=v"(d) : "v"(a), "v"(b), "v"(c));
    return d;
#endif
}

// rA = edge A regs (halfs), rB = edge B, dv = half2(dvA, dvB).
// perm sel: src1 bytes are idx 0..3, src0 bytes idx 4..7.
#define DOT8(rA, rB, dv)                                                        \
    acc[0] = dot2f(__builtin_amdgcn_perm(rB.x, rA.x, 0x05040100u), dv, acc[0]); \
    acc[1] = dot2f(__builtin_amdgcn_perm(rB.x, rA.x, 0x07060302u), dv, acc[1]); \
    acc[2] = dot2f(__builtin_amdgcn_perm(rB.y, rA.y, 0x05040100u), dv, acc[2]); \
    acc[3] = dot2f(__builtin_amdgcn_perm(rB.y, rA.y, 0x07060302u), dv, acc[3]); \
    acc[4] = dot2f(__builtin_amdgcn_perm(rB.z, rA.z, 0x05040100u), dv, acc[4]); \
    acc[5] = dot2f(__builtin_amdgcn_perm(rB.z, rA.z, 0x07060302u), dv, acc[5]); \
    acc[6] = dot2f(__builtin_amdgcn_perm(rB.w, rA.w, 0x05040100u), dv, acc[6]); \
    acc[7] = dot2f(__builtin_amdgcn_perm(rB.w, rA.w, 0x07060302u), dv, acc[7]);

__device__ __forceinline__ unsigned fenc(float f) {
    unsigned u = __float_as_uint(f);
    return u ^ (unsigned)(((int)u >> 31) | (int)0x80000000);
}
__device__ __forceinline__ float fdec(unsigned key) {
    return (key & 0x80000000u) ? __uint_as_float(key ^ 0x80000000u)
                               : __uint_as_float(~key);
}

// ---------------- Phase 1: per-slice degree count ----------------

__global__ __launch_bounds__(256) void k_cnt(const int* __restrict__ dst,
                                             int* __restrict__ cnt8) {
    __shared__ int cnt[NPG];
    int slice = blockIdx.x >> 3;
    int g = (blockIdx.x & 7) + 8 * (slice % 13);
    int sub = slice / 13;                     // 0..7
    if (g >= NB) return;
    int t = threadIdx.x;
    for (int i = t; i < NPG; i += 256) cnt[i] = 0;
    __syncthreads();
    int ebase = g * EPG + sub * 4000, nbase = g * NPG;
    for (int i = t; i < 4000; i += 256)
        atomicAdd(&cnt[dst[ebase + i] - nbase], 1);
    __syncthreads();
    for (int i = t; i < NPG; i += 256)
        cnt8[sub * N_NODES + nbase + i] = cnt[i];
}

// ---------------- Phase 2: deg sum, scan -> rowptr, dinv/dh16 ----------------

__global__ __launch_bounds__(1024) void k_scan(const int* __restrict__ cnt8,
                                               int* __restrict__ rowptr,
                                               float* __restrict__ dinv,
                                               unsigned short* __restrict__ dh16) {
    __shared__ int sm[1024];
    int g = (blockIdx.x & 7) + 8 * (blockIdx.x >> 3);
    if (g >= NB) return;
    int t = threadIdx.x;
    int nbase = g * NPG, ebase = g * EPG;
    int v = 0;
    if (t < NPG) {
        #pragma unroll
        for (int s8 = 0; s8 < 8; s8++) v += cnt8[s8 * N_NODES + nbase + t];
        float dv = rsqrtf((float)v + 2.0f);
        dinv[nbase + t] = dv;
        dh16[nbase + t] = __half_as_ushort(__float2half_rn(dv));
    }
    sm[t] = v;
    __syncthreads();
    for (int off = 1; off < 1024; off <<= 1) {
        int xx = (t >= off) ? sm[t - off] : 0;
        __syncthreads();
        sm[t] += xx;
        __syncthreads();
    }
    if (t < NPG)
        rowptr[nbase + t] = ebase + sm[t] - v;
    if (g == NB - 1 && t == 0) rowptr[N_NODES] = N_EDGES;
}

// ---------------- Phase 3 fused: LDS-staged edge scatter + MFMA GEMM1 ----------------
// blocks [0,416): sort quarter (g,q). blocks [416,832): gemm1, 250 rows each.
// Edge record: uint32 = (src_local*16) | (fp16(dinv[src]) << 16).

union SharedSG {
    struct {
        int cur[256];                            // LDS cursors (local offsets)
        unsigned buf[10000];                     // staged records
    } sc;
    struct {
        __align__(16) unsigned short wt[16384];  // fp16 W^T [c][k], swizzled
    } ge;
};

__global__ __launch_bounds__(1024) void k_sg(const int* __restrict__ src,
                                             const int* __restrict__ dst,
                                             const float* __restrict__ x,
                                             const float* __restrict__ Wa,
                                             const float* __restrict__ Wx,
                                             const int* __restrict__ rowptr,
                                             const unsigned short* __restrict__ dh16,
                                             unsigned int* __restrict__ esrc,
                                             unsigned short* __restrict__ h16) {
    __shared__ SharedSG S;
    int t = threadIdx.x;
    if (blockIdx.x < SORT_BLOCKS) {
        // ---------------- scatter path ----------------
        int xcd = blockIdx.x & 7, slot = blockIdx.x >> 3;
        int g = xcd + 8 * (slot % 13);
        int q = slot / 13;                       // node quarter 0..3
        if (g >= NB) return;
        int nbase = g * NPG, ebase = g * EPG;
        int n0 = q * 250;
        int base0 = rowptr[nbase + n0];
        int cap = rowptr[nbase + n0 + 250] - base0;
        if (t < 250)
            S.sc.cur[t] = rowptr[nbase + n0 + t] - base0;
        __syncthreads();
        for (int i = t; i < EPG; i += 1024) {
            int d = dst[ebase + i] - nbase - n0;
            if ((unsigned)d < 250u) {
                int s = src[ebase + i];
                int pos = atomicAdd(&S.sc.cur[d], 1);
                S.sc.buf[pos] = ((unsigned)(s - nbase) * 16) |
                                ((unsigned)dh16[s] << 16);
            }
        }
        __syncthreads();
        for (int i = t; i < cap; i += 1024)
            esrc[base0 + i] = S.sc.buf[i];
    } else {
        // ------------- gemm1 path (MFMA): h16 = fp16( x @ [W_a1 | W_x1] ) -------------
        int b2 = blockIdx.x - SORT_BLOCKS;         // 8*13*4 blocks
        int xcd = b2 & 7, slot = b2 >> 3;
        int g = xcd + 8 * (slot >> 2);
        int chunk = slot & 3;                       // 4 x 250-row chunks/graph
        if (g >= NB) return;
        int row0 = g * NPG + chunk * 250;
        // stage W^T fp16 in LDS, layout [c][k], byte ^= (c&7)<<4.
        {
            int cc = t & 127, kg = t >> 7;          // kg 0..7 -> k block of 16
            const float* Wp = (cc < 64) ? &Wa[cc] : &Wx[cc - 64];
            #pragma unroll
            for (int j = 0; j < 4; j++) {
                int k0 = kg * 16 + j * 4;
                union { __half h[4]; uint2 u; } pk;
                #pragma unroll
                for (int m = 0; m < 4; m++)
                    pk.h[m] = __float2half_rn(Wp[(k0 + m) * 64]);
                int byte = cc * 256 + ((2 * k0) ^ ((cc & 7) << 4));
                *(uint2*)((char*)S.ge.wt + byte) = pk.u;
            }
        }
        __syncthreads();
        int w = t >> 6, l = t & 63;
        int lr = l & 15, kq = l >> 4;               // A/B row|col, k-quarter
        int rowA = row0 + w * 16 + lr;
        int rA = rowA < N_NODES ? rowA : N_NODES - 1;
        const float* xr = &x[(size_t)rA * 128];
        h8_t a[4];
        #pragma unroll
        for (int kc = 0; kc < 4; kc++) {
            float4 lo = *(const float4*)&xr[kc * 32 + kq * 8];
            float4 hi = *(const float4*)&xr[kc * 32 + kq * 8 + 4];
            h8_t av;
            av[0] = (_Float16)lo.x; av[1] = (_Float16)lo.y;
            av[2] = (_Float16)lo.z; av[3] = (_Float16)lo.w;
            av[4] = (_Float16)hi.x; av[5] = (_Float16)hi.y;
            av[6] = (_Float16)hi.z; av[7] = (_Float16)hi.w;
            a[kc] = av;
        }
        f4_t acc[8] = {};
        #pragma unroll
        for (int kc = 0; kc < 4; kc++) {
            #pragma unroll
            for (int n = 0; n < 8; n++) {
                int cc = n * 16 + lr;
                int byte = cc * 256 + (((kc * 32 + kq * 8) * 2) ^ ((cc & 7) << 4));
                h8_t bf = *(h8_t*)((char*)S.ge.wt + byte);
                acc[n] = __builtin_amdgcn_mfma_f32_16x16x32_f16(a[kc], bf, acc[n], 0, 0, 0);
            }
        }
        // D: col = lane&15 (=lr), row = 4*kq + reg
        int rowD = row0 + w * 16 + kq * 4;
        #pragma unroll
        for (int n = 0; n < 8; n++) {
            #pragma unroll
            for (int j = 0; j < 4; j++) {
                int r = rowD + j;
                if (r < N_NODES)
                    h16[(size_t)r * 128 + n * 16 + lr] =
                        __half_as_ushort(__float2half_rn(acc[n][j]));
            }
        }
    }
}

// ---------------- Aggregation, 128 channels (layer 1) ----------------
// R20 structure (proven 56.5us): 16-lane group = 1 node; lane owns 8
// channels (uint4). 16 nodes/block, no cross-lane reduction, straight
// 8-edge unroll. No launch-bounds min-waves (R24's spill lesson).

__global__ __launch_bounds__(256) void k_agg128(const unsigned short* __restrict__ h16,
                                                const int* __restrict__ rowptr,
                                                const unsigned int* __restrict__ esrc,
                                                const float* __restrict__ dinv,
                                                const float* __restrict__ ba,
                                                const float* __restrict__ bx,
                                                unsigned short* __restrict__ outB16) {
    int xcd = blockIdx.x & 7, slot = blockIdx.x >> 3;
    int gi = slot / 63, chunk = slot - gi * 63;   // 63 chunks x 16 nodes
    int g = xcd + 8 * gi;
    if (g >= NB) return;
    int grp = threadIdx.x >> 4;    // node within block 0..15
    int cl  = threadIdx.x & 15;    // uint4 channel group
    int nl  = chunk * 16 + grp;
    int valid = nl < NPG;
    int nlc = valid ? nl : NPG - 1;
    int wid = g * NPG + nlc;
    const uint4* hg4 = (const uint4*)(h16 + (size_t)g * NPG * 128);
    float acc[8] = {};
    union U8 { uint4 u; __half h[8]; };
    int e0 = rowptr[wid];
    int e1 = valid ? rowptr[wid + 1] : e0;
    int e = e0;
    for (; e + 8 <= e1; e += 8) {
        unsigned pv0 = esrc[e + 0], pv1 = esrc[e + 1];
        unsigned pv2 = esrc[e + 2], pv3 = esrc[e + 3];
        unsigned pv4 = esrc[e + 4], pv5 = esrc[e + 5];
        unsigned pv6 = esrc[e + 6], pv7 = esrc[e + 7];
        uint4 r0 = hg4[(pv0 & 0xffffu) + cl];
        uint4 r1 = hg4[(pv1 & 0xffffu) + cl];
        uint4 r2 = hg4[(pv2 & 0xffffu) + cl];
        uint4 r3 = hg4[(pv3 & 0xffffu) + cl];
        uint4 r4 = hg4[(pv4 & 0xffffu) + cl];
        uint4 r5 = hg4[(pv5 & 0xffffu) + cl];
        uint4 r6 = hg4[(pv6 & 0xffffu) + cl];
        uint4 r7 = hg4[(pv7 & 0xffffu) + cl];
        unsigned dA = __builtin_amdgcn_perm(pv1, pv0, 0x07060302u);
        unsigned dB = __builtin_amdgcn_perm(pv3, pv2, 0x07060302u);
        unsigned dC = __builtin_amdgcn_perm(pv5, pv4, 0x07060302u);
        unsigned dD = __builtin_amdgcn_perm(pv7, pv6, 0x07060302u);
        DOT8(r0, r1, dA);
        DOT8(r2, r3, dB);
        DOT8(r4, r5, dC);
        DOT8(r6, r7, dD);
    }
    for (; e + 2 <= e1; e += 2) {
        unsigned pv0 = esrc[e], pv1 = esrc[e + 1];
        uint4 r0 = hg4[(pv0 & 0xffffu) + cl];
        uint4 r1 = hg4[(pv1 & 0xffffu) + cl];
        unsigned dA = __builtin_amdgcn_perm(pv1, pv0, 0x07060302u);
        DOT8(r0, r1, dA);
    }
    if (e < e1) {
        unsigned pv = esrc[e];
        uint4 r = hg4[(pv & 0xffffu) + cl];
        unsigned dA = pv >> 16;            // (dv, 0)
        DOT8(r, r, dA);
    }
    // epilogue (all lanes; no shuffles)
    float di = dinv[wid];
    float sw = 2.0f * di * di;
    U8 hv; hv.u = hg4[nlc * 16 + cl];
    int cl8 = cl * 8;
    const float* bb = (cl8 < 64) ? &ba[cl8] : &bx[cl8 - 64];
    union { __half2 h2[4]; uint4 q; } pk;
    #pragma unroll
    for (int k = 0; k < 4; k++) {
        float ox = fmaxf(di * acc[2 * k]     + sw * __half2float(hv.h[2 * k])     + bb[2 * k],     0.0f);
        float oy = fmaxf(di * acc[2 * k + 1] + sw * __half2float(hv.h[2 * k + 1]) + bb[2 * k + 1], 0.0f);
        pk.h2[k] = __floats2half2_rn(ox, oy);
    }
    if (valid)
        *(uint4*)&outB16[(size_t)wid * 128 + cl8] = pk.q;
}

// ---------------- Aggregation, 64 channels (layer 2) + col-max partials ----------------
// R20 structure: 8-lane group = 1 node (uint4 row of 8), 32 nodes/block.
// R25: emits per-block col maxes (cols 0..31, LDS atomicMax) -> pmax.

__global__ __launch_bounds__(256) void k_agg64(const unsigned short* __restrict__ g16,
                                               const int* __restrict__ rowptr,
                                               const unsigned int* __restrict__ esrc,
                                               const float* __restrict__ dinv,
                                               const float* __restrict__ ba2,
                                               const float* __restrict__ bx2,
                                               float* __restrict__ s2,
                                               float* __restrict__ pmax) {
    __shared__ unsigned pm[32];
    int xcd = blockIdx.x & 7, slot = blockIdx.x >> 3;
    int gi = slot >> 5, chunk = slot & 31;        // 32 chunks x 32 nodes
    int g = xcd + 8 * gi;
    if (g >= NB) return;
    int t = threadIdx.x;
    if (t < 32) pm[t] = 0u;
    __syncthreads();
    int grp = t >> 3;              // node within block 0..31
    int cl  = t & 7;               // uint4 channel group
    int nl  = chunk * 32 + grp;
    int valid = nl < NPG;
    int nlc = valid ? nl : NPG - 1;
    int wid = g * NPG + nlc;
    const uint4* gg4 = (const uint4*)(g16 + (size_t)g * NPG * 64);
    float acc[8] = {};
    union U8 { uint4 u; __half h[8]; };
    int e0 = rowptr[wid];
    int e1 = valid ? rowptr[wid + 1] : e0;
    int e = e0;
    for (; e + 8 <= e1; e += 8) {
        unsigned pv0 = esrc[e + 0], pv1 = esrc[e + 1];
        unsigned pv2 = esrc[e + 2], pv3 = esrc[e + 3];
        unsigned pv4 = esrc[e + 4], pv5 = esrc[e + 5];
        unsigned pv6 = esrc[e + 6], pv7 = esrc[e + 7];
        uint4 r0 = gg4[((pv0 & 0xffffu) >> 1) + cl];
        uint4 r1 = gg4[((pv1 & 0xffffu) >> 1) + cl];
        uint4 r2 = gg4[((pv2 & 0xffffu) >> 1) + cl];
        uint4 r3 = gg4[((pv3 & 0xffffu) >> 1) + cl];
        uint4 r4 = gg4[((pv4 & 0xffffu) >> 1) + cl];
        uint4 r5 = gg4[((pv5 & 0xffffu) >> 1) + cl];
        uint4 r6 = gg4[((pv6 & 0xffffu) >> 1) + cl];
        uint4 r7 = gg4[((pv7 & 0xffffu) >> 1) + cl];
        unsigned dA = __builtin_amdgcn_perm(pv1, pv0, 0x07060302u);
        unsigned dB = __builtin_amdgcn_perm(pv3, pv2, 0x07060302u);
        unsigned dC = __builtin_amdgcn_perm(pv5, pv4, 0x07060302u);
        unsigned dD = __builtin_amdgcn_perm(pv7, pv6, 0x07060302u);
        DOT8(r0, r1, dA);
        DOT8(r2, r3, dB);
        DOT8(r4, r5, dC);
        DOT8(r6, r7, dD);
    }
    for (; e + 2 <= e1; e += 2) {
        unsigned pv0 = esrc[e], pv1 = esrc[e + 1];
        uint4 r0 = gg4[((pv0 & 0xffffu) >> 1) + cl];
        uint4 r1 = gg4[((pv1 & 0xffffu) >> 1) + cl];
        unsigned dA = __builtin_amdgcn_perm(pv1, pv0, 0x07060302u);
        DOT8(r0, r1, dA);
    }
    if (e < e1) {
        unsigned pv = esrc[e];
        uint4 r = gg4[((pv & 0xffffu) >> 1) + cl];
        unsigned dA = pv >> 16;
        DOT8(r, r, dA);
    }
    float di = dinv[wid];
    float sw = 2.0f * di * di;
    U8 hv; hv.u = gg4[nlc * 8 + cl];
    int cl8 = cl * 8;
    float o[8];
    #pragma unroll
    for (int k = 0; k < 8; k++)
        o[k] = di * acc[k] + sw * __half2float(hv.h[k]);
    if (cl8 < 32) {
        #pragma unroll
        for (int k = 0; k < 8; k++) o[k] += ba2[cl8 + k];
    } else {
        #pragma unroll
        for (int k = 0; k < 8; k++) o[k] = fmaxf(o[k] + bx2[cl8 - 32 + k], 0.0f);
    }
    if (valid) {
        *(float4*)&s2[(size_t)wid * 64 + cl8]     = make_float4(o[0], o[1], o[2], o[3]);
        *(float4*)&s2[(size_t)wid * 64 + cl8 + 4] = make_float4(o[4], o[5], o[6], o[7]);
    }
    if (valid && cl < 4) {
        #pragma unroll
        for (int k = 0; k < 8; k++)
            atomicMax(&pm[cl8 + k], fenc(o[k]));
    }
    __syncthreads();
    if (t < 32)
        pmax[((size_t)g * 32 + chunk) * 32 + t] = fdec(pm[t]);
}

// ---------------- GEMM 2 (MFMA): g16 = fp16( b16 @ Wpad[128][64] ) ----------------
// Wpad = [[Wa2; 0], [0; Wx2]] (block-diag padded to K=128), fp16 in LDS
// transposed [c][k] with the gemm1 XOR swizzle. Inputs b16 already fp16.

__global__ __launch_bounds__(256) void k_gemm2(const unsigned short* __restrict__ Bm16,
                                               const float* __restrict__ Wa2,
                                               const float* __restrict__ Wx2,
                                               unsigned short* __restrict__ g16) {
    __shared__ __align__(16) unsigned short wt2[8192];   // 64 cols x 128 k, 16KB
    int xcd = blockIdx.x & 7, slot = blockIdx.x >> 3;
    int g = xcd + 8 * (slot >> 4);
    int chunk = slot & 15;
    if (g >= NB) return;
    int row0 = g * NPG + chunk * 64;   // chunk 15 spills into next graph: benign dup
    int t = threadIdx.x;
    {
        int cc = t & 63, kg = t >> 6;          // kg 0..3 -> k block of 32
        #pragma unroll
        for (int j = 0; j < 8; j++) {
            int k0 = kg * 32 + j * 4;
            union { __half h[4]; uint2 u; } pk;
            #pragma unroll
            for (int m = 0; m < 4; m++) {
                int k = k0 + m;
                float v;
                if (cc < 32) v = (k < 64)  ? Wa2[k * 32 + cc] : 0.0f;
                else         v = (k >= 64) ? Wx2[(k - 64) * 32 + (cc - 32)] : 0.0f;
                pk.h[m] = __float2half_rn(v);
            }
            int byte = cc * 256 + ((2 * k0) ^ ((cc & 7) << 4));
            *(uint2*)((char*)wt2 + byte) = pk.u;
        }
    }
    __syncthreads();
    int w = t >> 6, l = t & 63;
    int lr = l & 15, kq = l >> 4;
    int rowA = row0 + w * 16 + lr;
    int rA = rowA < N_NODES ? rowA : N_NODES - 1;
    const unsigned short* xr = &Bm16[(size_t)rA * 128];
    h8_t a[4];
    #pragma unroll
    for (int kc = 0; kc < 4; kc++)
        a[kc] = *(const h8_t*)&xr[kc * 32 + kq * 8];
    f4_t acc[4] = {};
    #pragma unroll
    for (int kc = 0; kc < 4; kc++) {
        #pragma unroll
        for (int n = 0; n < 4; n++) {
            int cc = n * 16 + lr;
            int byte = cc * 256 + (((kc * 32 + kq * 8) * 2) ^ ((cc & 7) << 4));
            h8_t bf = *(h8_t*)((char*)wt2 + byte);
            acc[n] = __builtin_amdgcn_mfma_f32_16x16x32_f16(a[kc], bf, acc[n], 0, 0, 0);
        }
    }
    int rowD = row0 + w * 16 + kq * 4;
    #pragma unroll
    for (int n = 0; n < 4; n++) {
        #pragma unroll
        for (int j = 0; j < 4; j++) {
            int r = rowD + j;
            if (r < N_NODES)
                g16[(size_t)r * 64 + n * 16 + lr] =
                    __half_as_ushort(__float2half_rn(acc[n][j]));
        }
    }
}

// ---------------- Bilinear pool: 8 chunks/graph; reduces pmax, emits psum ----------------

__global__ __launch_bounds__(256) void k_pool(const float* __restrict__ s2,
                                              const float* __restrict__ pmax,
                                              float* __restrict__ psum,
                                              float* __restrict__ prods) {
    __shared__ float ta[25][32];
    __shared__ float tx[25][32];
    __shared__ float gm[32];
    int xcd = blockIdx.x & 7, slot = blockIdx.x >> 3;
    int g = xcd + 8 * (slot >> 3);
    int ch = slot & 7;
    if (g >= NB) return;
    int t = threadIdx.x;
    if (t < 32) {
        float m = -1e30f;
        for (int j = 0; j < 32; j++)
            m = fmaxf(m, pmax[((size_t)g * 32 + j) * 32 + t]);
        gm[t] = m;
    }
    int e  = t >> 3;
    int f4 = t & 7;
    float a0 = 0.f, a1 = 0.f, a2 = 0.f, a3 = 0.f;
    float csum = 0.f;
    int base = g * NPG + ch * 125;
    for (int n0 = 0; n0 < 125; n0 += 25) {
        __syncthreads();
        for (int i = t; i < 25 * 16; i += 256) {
            int r = i >> 4, c4 = i & 15;
            float4 v = *(const float4*)&s2[(size_t)(base + n0 + r) * 64 + c4 * 4];
            if (c4 < 8) {
                int cb = c4 * 4;
                v.x = __expf(v.x - gm[cb + 0]);
                v.y = __expf(v.y - gm[cb + 1]);
                v.z = __expf(v.z - gm[cb + 2]);
                v.w = __expf(v.w - gm[cb + 3]);
                *(float4*)&ta[r][cb] = v;
            } else {
                *(float4*)&tx[r][(c4 - 8) * 4] = v;
            }
        }
        __syncthreads();
        if (t < 32) {
            #pragma unroll 5
            for (int r = 0; r < 25; r++) csum += ta[r][t];
        }
        #pragma unroll 5
        for (int n = 0; n < 25; n++) {
            float a   = ta[n][e];
            float4 xv = *(float4*)&tx[n][f4 * 4];
            a0 += a * xv.x; a1 += a * xv.y; a2 += a * xv.z; a3 += a * xv.w;
        }
    }
    if (t < 32)
        psum[((size_t)g * 8 + ch) * 32 + t] = csum;
    *(float4*)&prods[((size_t)(g * 8 + ch)) * 1024 + e * 32 + f4 * 4] =
        make_float4(a0, a1, a2, a3);
}

// ---------------- Head: fold psum -> 1/s, sum 8 chunk-partials, linear, softmax ----------------

__global__ __launch_bounds__(256) void k_head(const float* __restrict__ prods,
                                              const float* __restrict__ psum,
                                              const float* __restrict__ Wlin,
                                              const float* __restrict__ blin,
                                              float* __restrict__ out) {
    __shared__ float red[4][NCLS];
    __shared__ float sinvv[32];
    int g = (blockIdx.x & 7) + 8 * (blockIdx.x >> 3);
    if (g >= NB) return;
    int t = threadIdx.x;
    if (t < 32) {
        float s = 0.f;
        for (int q = 0; q < 8; q++) s += psum[((size_t)g * 8 + q) * 32 + t];
        sinvv[t] = 1.0f / s;
    }
    __syncthreads();
    float p[NCLS];
    for (int c = 0; c < NCLS; c++) p[c] = 0.0f;
    const float* pg = &prods[(size_t)g * 8 * 1024];
    for (int j = 0; j < 4; j++) {
        int k = t * 4 + j;
        int e = k >> 5;
        float v = 0.0f;
        #pragma unroll
        for (int q = 0; q < 8; q++) v += pg[q * 1024 + k];
        v *= sinvv[e];
        const float* wrow = &Wlin[k * NCLS];
        for (int c = 0; c < NCLS; c++) p[c] += v * wrow[c];
    }
    for (int off = 32; off > 0; off >>= 1)
        for (int c = 0; c < NCLS; c++) p[c] += __shfl_down(p[c], off, 64);
    int wave = t >> 6, lane = t & 63;
    if (lane == 0)
        for (int c = 0; c < NCLS; c++) red[wave][c] = p[c];
    __syncthreads();
    if (t == 0) {
        float logits[NCLS]; float mx = -1e30f;
        for (int c = 0; c < NCLS; c++) {
            logits[c] = red[0][c] + red[1][c] + red[2][c] + red[3][c] + blin[c];
            mx = fmaxf(mx, logits[c]);
        }
        float s = 0.0f;
        for (int c = 0; c < NCLS; c++) { logits[c] = expf(logits[c] - mx); s += logits[c]; }
        float inv = 1.0f / s;
        for (int c = 0; c < NCLS; c++) out[g * NCLS + c] = logits[c] * inv;
    }
}

// ---------------- launch ----------------

extern "C" void kernel_launch(void* const* d_in, const int* in_sizes, int n_in,
                              void* d_out, int out_size, void* d_ws, size_t ws_size,
                              hipStream_t stream) {
    const float* x    = (const float*)d_in[0];
    const int*   ei   = (const int*)d_in[1];
    const float* Wa1  = (const float*)d_in[3];
    const float* ba1  = (const float*)d_in[4];
    const float* Wa2  = (const float*)d_in[5];
    const float* ba2  = (const float*)d_in[6];
    const float* Wx1  = (const float*)d_in[7];
    const float* bx1  = (const float*)d_in[8];
    const float* Wx2  = (const float*)d_in[9];
    const float* bx2  = (const float*)d_in[10];
    const float* Wlin = (const float*)d_in[11];
    const float* blin = (const float*)d_in[12];
    float* out = (float*)d_out;

    char* w = (char*)d_ws;
    auto alloc = [&](size_t bytes) -> void* {
        void* p = (void*)w;
        w += (bytes + 255) & ~(size_t)255;
        return p;
    };
    int*            rowptr = (int*)alloc((N_NODES + 1) * sizeof(int));
    int*            cnt8   = (int*)alloc((size_t)8 * N_NODES * sizeof(int));
    float*          dinv   = (float*)alloc(N_NODES * sizeof(float));
    unsigned short* dh16   = (unsigned short*)alloc(N_NODES * sizeof(unsigned short));
    unsigned int*   esrc   = (unsigned int*)alloc((size_t)N_EDGES * sizeof(unsigned int));
    float*          pmax   = (float*)alloc((size_t)NB * 32 * 32 * sizeof(float));
    float*          psum   = (float*)alloc((size_t)NB * 8 * 32 * sizeof(float));
    float*          prods  = (float*)alloc((size_t)NB * 8 * 1024 * sizeof(float));
    unsigned short* h16    = (unsigned short*)alloc((size_t)N_NODES * 128 * sizeof(unsigned short));
    unsigned short* b16    = (unsigned short*)alloc((size_t)N_NODES * 128 * sizeof(unsigned short));
    unsigned short* g16    = (unsigned short*)alloc((size_t)N_NODES * 64 * sizeof(unsigned short));
    float*          s2     = (float*)alloc((size_t)N_NODES * 64 * sizeof(float));

    const int* srcp = ei;
    const int* dstp = ei + N_EDGES;

    k_cnt<<<CNT_BLOCKS, 256, 0, stream>>>(dstp, cnt8);
    k_scan<<<8 * 13, 1024, 0, stream>>>(cnt8, rowptr, dinv, dh16);
    k_sg<<<SORT_BLOCKS + 8 * 13 * 4, 1024, 0, stream>>>(srcp, dstp, x, Wa1, Wx1,
                                                        rowptr, dh16, esrc, h16);
    k_agg128<<<8 * 13 * 63, 256, 0, stream>>>(h16, rowptr, esrc, dinv, ba1, bx1, b16);
    k_gemm2<<<8 * 13 * 16, 256, 0, stream>>>(b16, Wa2, Wx2, g16);
    k_agg64<<<8 * 13 * 32, 256, 0, stream>>>(g16, rowptr, esrc, dinv, ba2, bx2, s2, pmax);
    k_pool<<<8 * 13 * 8, 256, 0, stream>>>(s2, pmax, psum, prods);
    k_head<<<8 * 13, 256, 0, stream>>>(prods, psum, Wlin, blin, out);
}